// Round 6
// baseline (533.074 us; speedup 1.0000x reference)
//
#include <hip/hip_runtime.h>
#include <math.h>

#define NFEAT 128
#define NCLS 40
#define NCLSP 64      // padded class dim (bf16) for pow2 lane math
#define BINROWS 64    // rows per bin
#define NBINMAX 1600  // >= ceil(100000/64)=1563
#define NBLKC 256     // chunks for the binning sort
#define CHUNKMAX 6400 // >= ceil(1600000/256)=6250 ; LDS stage = 50KB
#define SEGC 7        // ceil(NBINMAX/256)
#define RSMAX 2048    // per-bin capacity in bins2 (fixed stride) + row_sort LDS stage

typedef short bf16x8 __attribute__((ext_vector_type(8)));
typedef float f32x4 __attribute__((ext_vector_type(4)));

// ---------- bf16 helpers ----------
__device__ __forceinline__ float bf2f(unsigned int lo16) {
  return __uint_as_float((lo16 & 0xffffu) << 16);
}
__device__ __forceinline__ unsigned int f2bf(float x) {  // round-to-nearest-even
  unsigned int u = __float_as_uint(x);
  return (u + 0x7fffu + ((u >> 16) & 1u)) >> 16;
}

// ============================ merged prep: BN fold + W conv + x*M conv ============================
// block 0: BN fold; blocks 1..20: W0/W1 bf16 + W2 hi/lo split; blocks 21..: x*M -> bf16.
__global__ __launch_bounds__(256) void prep_all(
    const float* b0, const float* g0, const float* be0,
    const float* rm0, const float* rv0,
    const float* b1, const float* g1, const float* be1,
    const float* rm1, const float* rv1,
    float* sc0, float* sh0, float* sc1, float* sh1,
    const float* __restrict__ W0, const float* __restrict__ W1,
    const float* __restrict__ W2,
    unsigned short* __restrict__ Wb0, unsigned short* __restrict__ Wb1,
    unsigned short* __restrict__ W2hi, unsigned short* __restrict__ W2lo,
    const float* __restrict__ x, const float* __restrict__ Mv,
    unsigned short* __restrict__ xm, int n) {
  int t = threadIdx.x;
  if (blockIdx.x == 0) {
    if (t < 128) {
      float s = g0[t] * rsqrtf(rv0[t] + 1e-5f);
      sc0[t] = s;
      sh0[t] = (b0[t] - rm0[t]) * s + be0[t];
    } else {
      int i = t - 128;
      float s = g1[i] * rsqrtf(rv1[i] + 1e-5f);
      sc1[i] = s;
      sh1[i] = (b1[i] - rm1[i]) * s + be1[i];
    }
    return;
  }
  if (blockIdx.x <= 20) {
    int i = (blockIdx.x - 1) * 256 + t;  // 5120 threads, 8 elems each
    if (i < 4096) {
      const float* W = (i < 2048) ? W0 : W1;
      unsigned short* Wb = (i < 2048) ? Wb0 : Wb1;
      int j = (i < 2048) ? i : i - 2048;
      const float4* p = (const float4*)(W + (size_t)j * 8);
      float4 v0 = p[0], v1 = p[1];
      unsigned int o0 = f2bf(v0.x) | (f2bf(v0.y) << 16);
      unsigned int o1 = f2bf(v0.z) | (f2bf(v0.w) << 16);
      unsigned int o2 = f2bf(v1.x) | (f2bf(v1.y) << 16);
      unsigned int o3 = f2bf(v1.z) | (f2bf(v1.w) << 16);
      ((uint4*)Wb)[j] = make_uint4(o0, o1, o2, o3);
    } else {
      int j = i - 4096;  // chunk of 8 within padded 64x128
      int r = j >> 4;    // padded out-row
      float v[8] = {0.f, 0.f, 0.f, 0.f, 0.f, 0.f, 0.f, 0.f};
      if (r < NCLS) {  // j*8 == r*128 + (j&15)*8 exactly
        const float4* p = (const float4*)(W2 + (size_t)j * 8);
        float4 a = p[0], b = p[1];
        v[0] = a.x; v[1] = a.y; v[2] = a.z; v[3] = a.w;
        v[4] = b.x; v[5] = b.y; v[6] = b.z; v[7] = b.w;
      }
      unsigned int h[8], l[8];
#pragma unroll
      for (int q = 0; q < 8; ++q) {
        h[q] = f2bf(v[q]);
        l[q] = f2bf(v[q] - bf2f(h[q]));
      }
      ((uint4*)W2hi)[j] = make_uint4(h[0] | (h[1] << 16), h[2] | (h[3] << 16),
                                     h[4] | (h[5] << 16), h[6] | (h[7] << 16));
      ((uint4*)W2lo)[j] = make_uint4(l[0] | (l[1] << 16), l[2] | (l[3] << 16),
                                     l[4] | (l[5] << 16), l[6] | (l[7] << 16));
    }
    return;
  }
  int i = (blockIdx.x - 21) * 256 + t;  // one 8-elem chunk per thread
  if (i >= n * (NFEAT / 8)) return;
  int row = i >> 4;
  float m = Mv[row];
  const float4* p = (const float4*)(x + (size_t)i * 8);
  float4 v0 = p[0], v1 = p[1];
  unsigned int o0 = f2bf(v0.x * m) | (f2bf(v0.y * m) << 16);
  unsigned int o1 = f2bf(v0.z * m) | (f2bf(v0.w * m) << 16);
  unsigned int o2 = f2bf(v1.x * m) | (f2bf(v1.y * m) << 16);
  unsigned int o3 = f2bf(v1.z * m) | (f2bf(v1.w * m) << 16);
  ((uint4*)xm)[i] = make_uint4(o0, o1, o2, o3);
}

// ============================ stage 1 (merged Z+A): chunk -> 64-row bins ============================
// LDS staging is LOAD-BEARING: it converts the random-within-50KB scatter into
// linear full-cacheline global writes. Removing it (round 3) caused ~6x write
// amplification (WRITE_SIZE 26MB -> 144MB) and 2x kernel time. Do not remove.
__global__ __launch_bounds__(256) void bin_sort2(
    const int* __restrict__ srcZ, const int* __restrict__ dstZ, const float* __restrict__ valZ,
    const int* __restrict__ srcA, const int* __restrict__ dstA, const float* __restrict__ valA,
    int2* __restrict__ DrmZ, int2* __restrict__ DrmA,
    int2* __restrict__ binsCZ, int2* __restrict__ binsCA,
    int E, int nbin, int chunk) {
  __shared__ int2 stage[CHUNKMAX];
  __shared__ int cur[NBINMAX];
  __shared__ int ps[256];
  const int t = threadIdx.x;
  int k = blockIdx.x;
  const int* srcp; const int* dstp; const float* valp; int2* Drm; int2* binsC;
  if (k < NBLKC) {
    srcp = srcZ; dstp = dstZ; valp = valZ; Drm = DrmZ; binsC = binsCZ;
  } else {
    k -= NBLKC;
    srcp = srcA; dstp = dstA; valp = valA; Drm = DrmA; binsC = binsCA;
  }
  for (int i = t; i < nbin; i += 256) cur[i] = 0;
  __syncthreads();
  const int e0 = k * chunk, e1 = min(E, e0 + chunk);
#pragma unroll 4
  for (int e = e0 + t; e < e1; e += 256) atomicAdd(&cur[dstp[e] >> 6], 1);
  __syncthreads();
  int loc[SEGC], cnt[SEGC];
  int s = 0;
#pragma unroll
  for (int j = 0; j < SEGC; ++j) {
    int i = t * SEGC + j;
    int v = (i < nbin) ? cur[i] : 0;
    loc[j] = s; cnt[j] = v;
    s += v;
  }
  ps[t] = s;
  __syncthreads();
  for (int o = 1; o < 256; o <<= 1) {
    int x = (t >= o) ? ps[t - o] : 0;
    __syncthreads();
    ps[t] += x;
    __syncthreads();
  }
  int ex = ps[t] - s;
#pragma unroll
  for (int j = 0; j < SEGC; ++j) {
    int i = t * SEGC + j;
    if (i < nbin) {
      int o = ex + loc[j];
      Drm[(size_t)k * nbin + i] = make_int2(e0 + o, cnt[j]);
      cur[i] = o;
    }
  }
  __syncthreads();
#pragma unroll 2
  for (int e = e0 + t; e < e1; e += 256) {
    int d = dstp[e];
    int p = atomicAdd(&cur[d >> 6], 1);
    stage[p] = make_int2(srcp[e] | ((d & 63) << 17), __float_as_int(valp[e]));
  }
  __syncthreads();
  const int n = e1 - e0;
  for (int i = t; i < n; i += 256) binsC[e0 + i] = stage[i];
}

// Transpose run descriptors (row-major by chunk -> bin-major). Merged Z+A.
__global__ __launch_bounds__(256) void transposeD2(
    const int2* __restrict__ DrmZ, const int2* __restrict__ DrmA,
    int2* __restrict__ DbmZ, int2* __restrict__ DbmA, int nbin, int tdb) {
  __shared__ int2 st[8][256];
  int t = threadIdx.x;
  int b = blockIdx.x;
  const int2* Drm; int2* Dbm;
  if (b < tdb) {
    Drm = DrmZ; Dbm = DbmZ;
  } else {
    b -= tdb;
    Drm = DrmA; Dbm = DbmA;
  }
  int i0 = b * 8;
#pragma unroll
  for (int j = 0; j < 8; ++j) {
    int i = i0 + j;
    st[j][t] = (i < nbin) ? Drm[(size_t)t * nbin + i] : make_int2(0, 0);
  }
  __syncthreads();
  {
    int j = t >> 5, ks = (t & 31) * 8;
    int i = i0 + j;
    if (i < nbin) {
      int2* q = &Dbm[(size_t)i * NBLKC + ks];
#pragma unroll
      for (int m = 0; m < 8; ++m) q[m] = st[j][ks + m];
    }
  }
}

// ============================ stage 2 (merged Z+A): bin -> full dst-row sort ============================
// bins2 layout: bin b occupies [b*RSMAX, b*RSMAX+cnt). rowdesc[row] = (start, deg).
__global__ __launch_bounds__(256) void row_sort2(
    const int2* __restrict__ DbmZ, const int2* __restrict__ DbmA,
    const int2* __restrict__ binsCZ, const int2* __restrict__ binsCA,
    int2* __restrict__ bins2Z, int2* __restrict__ bins2A,
    int2* __restrict__ rdZ, int2* __restrict__ rdA, int n, int nbin) {
  __shared__ int2 stage[RSMAX];
  __shared__ int ps[256];
  __shared__ int rcnt[BINROWS];
  __shared__ int roff[BINROWS];
  int b = blockIdx.x;
  const int t = threadIdx.x;
  const int2* Dbm; const int2* binsC; int2* bins2; int2* rowdesc;
  if (b < nbin) {
    Dbm = DbmZ; binsC = binsCZ; bins2 = bins2Z; rowdesc = rdZ;
  } else {
    b -= nbin;
    Dbm = DbmA; binsC = binsCA; bins2 = bins2A; rowdesc = rdA;
  }
  if (t < BINROWS) rcnt[t] = 0;
  int2 run = Dbm[(size_t)b * NBLKC + t];
  ps[t] = run.y;
  __syncthreads();
  for (int o = 1; o < 256; o <<= 1) {
    int x = (t >= o) ? ps[t - o] : 0;
    __syncthreads();
    ps[t] += x;
    __syncthreads();
  }
  int mystart = ps[t] - run.y;
  for (int j = 0; j < run.y; ++j) {
    int2 en = binsC[run.x + j];
    int idx = mystart + j;
    if (idx < RSMAX) stage[idx] = en;
    atomicAdd(&rcnt[(en.x >> 17) & 63], 1);
  }
  __syncthreads();
  const int bs = b * RSMAX;
  if (t < BINROWS) {  // wave 0 only: scan 64 row counts
    int c = rcnt[t];
    int s = c;
#pragma unroll
    for (int o = 1; o < 64; o <<= 1) {
      int v = __shfl_up(s, o);
      if (t >= o) s += v;
    }
    int excl = s - c;
    int row = b * BINROWS + t;
    if (row < n) rowdesc[row] = make_int2(bs + excl, c);
    roff[t] = excl;
  }
  __syncthreads();
  int total = min(ps[255], RSMAX);
  for (int i = t; i < total; i += 256) {
    int2 en = stage[i];
    int row = (en.x >> 17) & 63;
    int p = atomicAdd(&roff[row], 1);
    bins2[bs + p] = en;
  }
}

// ============================ fused SPMM + MFMA GEMM (mega kernel) ============================
// Per wave: run the SACRED spmm inner loop (unchanged) for 16 consecutive rows,
// parking each bf16 row in a wave-private LDS tile [16][136]; then the GEMM
// phase consumes the tile as MFMA A-fragments. All LDS accesses are
// wave-private -> NO block barriers; waves stay fully independent (preserves
// spmm scheduling behavior). Eliminates the 25.6MB Y write + 25.6MB Y re-read
// per layer vs the split kernels.
// LAYER0: scale by AM, GEMM W0 + BN + ReLU -> write H (N x 128 bf16).
// !LAYER0: GEMM W1 + BN + ReLU -> H1 overwrites the LDS tile in place (all
//          A-reads done), then GEMM W2hi/lo (fp32-split) -> write G2 (N x 64).
template <bool LAYER0>
__global__ __launch_bounds__(128) void spmm_gemm128(
    const int2* __restrict__ rowdesc, const int2* __restrict__ bins2,
    const unsigned short* __restrict__ X, const float* __restrict__ AM,
    const unsigned short* __restrict__ Wb,
    const float* __restrict__ scale, const float* __restrict__ shift,
    const unsigned short* __restrict__ Whi, const unsigned short* __restrict__ Wlo,
    unsigned short* __restrict__ Out, int n) {
  __shared__ unsigned short Yt[32][136];  // 2 waves x wave-private [16][136]
  const int wave = threadIdx.x >> 6;
  const int lane = threadIdx.x & 63;
  const int half = lane >> 5, l32 = lane & 31;
  const int r0 = blockIdx.x * 32 + wave * 16;

  // ---- spmm phase: 16 rows, sacred inner loop untouched ----
#pragma unroll 1
  for (int j = 0; j < 16; ++j) {
    int row = r0 + j;
    float s0 = 0.f, s1 = 0.f, s2 = 0.f, s3 = 0.f;
    if (row < n) {
      int2 rd = rowdesc[row];
      int s = rd.x, d = rd.y;
      for (int kb = 0; kb < d; kb += 64) {
        int rem = min(64, d - kb);
        int2 my = (lane < rem) ? bins2[s + kb + lane] : make_int2(0, 0);  // w==0 pads
        int myc = my.x & 0x1FFFF;
        float myw = __int_as_float(my.y);
        for (int k = 0; k < rem; k += 8) {
#pragma unroll
          for (int st = 0; st < 4; ++st) {
            int idx = k + 2 * st + half;  // <= 63; pad entries have w==0
            int c = __shfl(myc, idx);
            float wv = __shfl(myw, idx);
            uint2 pv = *(const uint2*)(X + (size_t)c * NFEAT + l32 * 4);
            s0 += wv * bf2f(pv.x);
            s1 += wv * bf2f(pv.x >> 16);
            s2 += wv * bf2f(pv.y);
            s3 += wv * bf2f(pv.y >> 16);
          }
        }
      }
      s0 += __shfl_xor(s0, 32); s1 += __shfl_xor(s1, 32);
      s2 += __shfl_xor(s2, 32); s3 += __shfl_xor(s3, 32);
      if (LAYER0) {
        float am = AM[row];
        s0 *= am; s1 *= am; s2 *= am; s3 *= am;
      }
    }
    unsigned int pk = half ? (f2bf(s2) | (f2bf(s3) << 16)) : (f2bf(s0) | (f2bf(s1) << 16));
    *(unsigned int*)&Yt[wave * 16 + j][(l32 * 2 + half) * 2] = pk;  // zero rows for j >= n
  }

  // ---- GEMM phase: A from wave-private LDS; B from global (L2-hot) ----
  const int quad = lane >> 4, l16 = lane & 15;
  const int orow0 = r0 + quad * 4;
  f32x4 acc[8];
#pragma unroll
  for (int c = 0; c < 8; ++c) acc[c] = (f32x4){0.f, 0.f, 0.f, 0.f};
#pragma unroll
  for (int kc = 0; kc < 4; ++kc) {
    bf16x8 a = *(const bf16x8*)&Yt[wave * 16 + l16][kc * 32 + quad * 8];
#pragma unroll
    for (int c = 0; c < 8; ++c) {
      bf16x8 b = *(const bf16x8*)(Wb + (size_t)(c * 16 + l16) * 128 + kc * 32 + quad * 8);
      acc[c] = __builtin_amdgcn_mfma_f32_16x16x32_bf16(a, b, acc[c], 0, 0, 0);
    }
  }

  if constexpr (LAYER0) {
#pragma unroll
    for (int c = 0; c < 8; ++c) {
      int col = c * 16 + l16;
      float sc = scale[col], sh = shift[col];
#pragma unroll
      for (int r = 0; r < 4; ++r) {
        int orow = orow0 + r;
        if (orow < n) {
          float v = fmaxf(acc[c][r] * sc + sh, 0.f);
          Out[(size_t)orow * 128 + col] = (unsigned short)f2bf(v);
        }
      }
    }
  } else {
    // H1 = relu(bn(acc)) overwrites the wave-private tile (all A-reads done).
#pragma unroll
    for (int c = 0; c < 8; ++c) {
      int col = c * 16 + l16;
      float sc = scale[col], sh = shift[col];
#pragma unroll
      for (int r = 0; r < 4; ++r) {
        float v = fmaxf(acc[c][r] * sc + sh, 0.f);
        Yt[wave * 16 + quad * 4 + r][col] = (unsigned short)f2bf(v);
      }
    }
    // G2 = H1 @ W2pad^T (hi+lo bf16 split of fp32 W2; 64 padded cols)
    f32x4 acc2[4];
#pragma unroll
    for (int c2 = 0; c2 < 4; ++c2) acc2[c2] = (f32x4){0.f, 0.f, 0.f, 0.f};
#pragma unroll
    for (int kc = 0; kc < 4; ++kc) {
      bf16x8 hf = *(const bf16x8*)&Yt[wave * 16 + l16][kc * 32 + quad * 8];
#pragma unroll
      for (int c2 = 0; c2 < 4; ++c2) {
        bf16x8 bh = *(const bf16x8*)(Whi + (size_t)(c2 * 16 + l16) * 128 + kc * 32 + quad * 8);
        bf16x8 bl = *(const bf16x8*)(Wlo + (size_t)(c2 * 16 + l16) * 128 + kc * 32 + quad * 8);
        acc2[c2] = __builtin_amdgcn_mfma_f32_16x16x32_bf16(hf, bh, acc2[c2], 0, 0, 0);
        acc2[c2] = __builtin_amdgcn_mfma_f32_16x16x32_bf16(hf, bl, acc2[c2], 0, 0, 0);
      }
    }
#pragma unroll
    for (int c2 = 0; c2 < 4; ++c2) {
      int col = c2 * 16 + l16;
#pragma unroll
      for (int r = 0; r < 4; ++r) {
        int orow = orow0 + r;
        if (orow < n) Out[(size_t)orow * NCLSP + col] = (unsigned short)f2bf(acc2[c2][r]);
      }
    }
  }
}

// ============================ final: spmm(40) + bias + log_softmax ============================
__global__ __launch_bounds__(256) void spmm_softmax64(
    const int2* __restrict__ rowdesc, const int2* __restrict__ bins2,
    const unsigned short* __restrict__ G2, const float* __restrict__ b2,
    float* __restrict__ out, int n) {
  int row = (blockIdx.x * 256 + threadIdx.x) >> 6;
  int lane = threadIdx.x & 63;
  if (row >= n) return;
  const int eidx = lane >> 4, q = lane & 15;
  const bool vq = q < (NCLS / 4);  // 10 quartets cover the 40 real classes
  float4 bv = vq ? *(const float4*)(b2 + q * 4) : make_float4(0.f, 0.f, 0.f, 0.f);

  int2 rdv = rowdesc[row];
  int s0i = rdv.x, d = rdv.y;
  float a0 = 0.f, a1 = 0.f, a2 = 0.f, a3 = 0.f;
  for (int kb = 0; kb < d; kb += 64) {
    int rem = min(64, d - kb);
    int2 my = (lane < rem) ? bins2[s0i + kb + lane] : make_int2(0, 0);
    int myc = my.x & 0x1FFFF;
    float myw = __int_as_float(my.y);
    int steps = (rem + 3) >> 2;
#pragma unroll 4
    for (int st = 0; st < steps; ++st) {
      int idx = st * 4 + eidx;  // <= 63; pad entries have w==0
      int c = __shfl(myc, idx);
      float wv = __shfl(myw, idx);
      uint2 pv = *(const uint2*)(G2 + (size_t)c * NCLSP + q * 4);
      a0 += wv * bf2f(pv.x);
      a1 += wv * bf2f(pv.x >> 16);
      a2 += wv * bf2f(pv.y);
      a3 += wv * bf2f(pv.y >> 16);
    }
  }
  a0 += __shfl_xor(a0, 16); a1 += __shfl_xor(a1, 16);
  a2 += __shfl_xor(a2, 16); a3 += __shfl_xor(a3, 16);
  a0 += __shfl_xor(a0, 32); a1 += __shfl_xor(a1, 32);
  a2 += __shfl_xor(a2, 32); a3 += __shfl_xor(a3, 32);
  float z0 = a0 + bv.x, z1 = a1 + bv.y, z2 = a2 + bv.z, z3 = a3 + bv.w;
  bool par = (eidx == 0) && vq;
  float m = par ? fmaxf(fmaxf(z0, z1), fmaxf(z2, z3)) : -INFINITY;
#pragma unroll
  for (int o = 1; o < 64; o <<= 1) m = fmaxf(m, __shfl_xor(m, o));
  float ex = par ? (__expf(z0 - m) + __expf(z1 - m) + __expf(z2 - m) + __expf(z3 - m)) : 0.f;
#pragma unroll
  for (int o = 1; o < 64; o <<= 1) ex += __shfl_xor(ex, o);
  float lg = m + __logf(ex);
  if (par) {
    *(float4*)&out[(size_t)row * NCLS + q * 4] =
        make_float4(z0 - lg, z1 - lg, z2 - lg, z3 - lg);
  }
}

// ============================ launch ============================

extern "C" void kernel_launch(void* const* d_in, const int* in_sizes, int n_in,
                              void* d_out, int out_size, void* d_ws, size_t ws_size,
                              hipStream_t stream) {
  const float* x    = (const float*)d_in[0];
  const float* Mv   = (const float*)d_in[1];
  const float* AM   = (const float*)d_in[2];
  const int* srcZ   = (const int*)d_in[3];
  const int* dstZ   = (const int*)d_in[4];
  const float* valsZ= (const float*)d_in[5];
  const int* src    = (const int*)d_in[6];
  const int* dst    = (const int*)d_in[7];
  const float* vals = (const float*)d_in[8];
  const float* W0   = (const float*)d_in[9];
  const float* b0   = (const float*)d_in[10];
  const float* g0   = (const float*)d_in[11];
  const float* be0  = (const float*)d_in[12];
  const float* rm0  = (const float*)d_in[13];
  const float* rv0  = (const float*)d_in[14];
  const float* W1   = (const float*)d_in[15];
  const float* b1   = (const float*)d_in[16];
  const float* g1   = (const float*)d_in[17];
  const float* be1  = (const float*)d_in[18];
  const float* rm1  = (const float*)d_in[19];
  const float* rv1  = (const float*)d_in[20];
  const float* W2   = (const float*)d_in[21];
  const float* b2   = (const float*)d_in[22];
  float* out = (float*)d_out;

  const int N = in_sizes[1];  // M has shape (N,1)
  const int E = in_sizes[3];
  const int NBIN = (N + BINROWS - 1) / BINROWS;
  const int CHUNK = (E + NBLKC - 1) / NBLKC;  // 6250 <= CHUNKMAX

  char* w = (char*)d_ws;
  size_t off = 0;
  auto alloc = [&](size_t bytes) -> void* {
    void* p = w + off;
    off = (off + bytes + 255) & ~(size_t)255;
    return p;
  };
  const size_t bins2Bytes = (size_t)NBIN * RSMAX * 8;     // 25.6MB fixed-stride layout
  const size_t bufBytes = (size_t)N * NFEAT * 2;          // 25.6MB
  int2* binsCZ = (int2*)alloc((size_t)NBLKC * CHUNK * 8); // 12.8MB chunk-ordered stage (Z)
  int2* binsCA = (int2*)alloc((size_t)NBLKC * CHUNK * 8); // 12.8MB chunk-ordered stage (A)
  int2* bins2A = (int2*)alloc(bins2Bytes);                // lives to the end
  int2* rdZ = (int2*)alloc((size_t)N * 8);                // rowdesc (start,deg) Z
  int2* rdA = (int2*)alloc((size_t)N * 8);                // rowdesc (start,deg) A
  unsigned short* xm = (unsigned short*)alloc(bufBytes);  // 25.6MB; G2 reuses after mega0
  unsigned short* bufA = (unsigned short*)alloc(bufBytes);                 // Drm/Dbm -> H0
  unsigned short* bufB = (unsigned short*)alloc(bins2Bytes > bufBytes ? bins2Bytes : bufBytes);
  float* sc0 = (float*)alloc(128 * 4);
  float* sh0 = (float*)alloc(128 * 4);
  float* sc1 = (float*)alloc(128 * 4);
  float* sh1 = (float*)alloc(128 * 4);
  unsigned short* Wb0 = (unsigned short*)alloc(128 * 128 * 2);
  unsigned short* Wb1 = (unsigned short*)alloc(128 * 128 * 2);
  unsigned short* W2hi = (unsigned short*)alloc(64 * 128 * 2);
  unsigned short* W2lo = (unsigned short*)alloc(64 * 128 * 2);
  // aliases (all lifetimes disjoint within each kernel -- no same-kernel R/W overlap):
  //  - Drm/Dbm (x2, 3.2MB each) live in bufA until row_sort2 done; mega0 then
  //    writes H0 into bufA.
  //  - bins2Z (25.6MB fixed-stride) lives in bufB; consumed by mega0 (reads
  //    bins2Z + xm, writes bufA). bufB dead afterwards.
  //  - mega1 reads bufA (H0) + bins2A, writes G2 into xm (dead after mega0).
  const size_t drmBytes = (size_t)NBLKC * NBIN * 8;  // 3,201,024 (mult of 256)
  int2* DrmZ = (int2*)((char*)bufA + 0 * drmBytes);
  int2* DrmA = (int2*)((char*)bufA + 1 * drmBytes);
  int2* DbmZ = (int2*)((char*)bufA + 2 * drmBytes);
  int2* DbmA = (int2*)((char*)bufA + 3 * drmBytes);
  int2* bins2Z = (int2*)bufB;
  unsigned short* G2 = xm;

  const int RB = (N + 3) / 4;        // softmax: 4 rows (waves) per 256-thread block
  const int MB32 = (N + 31) / 32;    // mega: 32 rows per 128-thread block (2 waves x 16)
  const int TDB = (NBIN + 7) / 8;
  const int CONVB = (N * (NFEAT / 8) + 255) / 256;

  prep_all<<<21 + CONVB, 256, 0, stream>>>(b0, g0, be0, rm0, rv0, b1, g1, be1, rm1, rv1,
                                           sc0, sh0, sc1, sh1, W0, W1, W2,
                                           Wb0, Wb1, W2hi, W2lo, x, Mv, xm, N);

  // --- both adjacencies: chunk-bin sort -> full row sort (merged launches) ---
  bin_sort2<<<2 * NBLKC, 256, 0, stream>>>(srcZ, dstZ, valsZ, src, dst, vals,
                                           DrmZ, DrmA, binsCZ, binsCA, E, NBIN, CHUNK);
  transposeD2<<<2 * TDB, 256, 0, stream>>>(DrmZ, DrmA, DbmZ, DbmA, NBIN, TDB);
  row_sort2<<<2 * NBIN, 256, 0, stream>>>(DbmZ, DbmA, binsCZ, binsCA,
                                          bins2Z, bins2A, rdZ, rdA, N, NBIN);

  // layer 0 (fused): H0 = relu(bn(spmm(adjZ, M*x)*AM @ W0^T + b0)) -> bufA
  spmm_gemm128<true><<<MB32, 128, 0, stream>>>(rdZ, bins2Z, xm, AM, Wb0, sc0, sh0,
                                               nullptr, nullptr, bufA, N);

  // layer 1+2 (fused): Y1 = spmm(adj, H0); H1 = relu(bn(Y1 @ W1^T + b1)) on-chip;
  // G2 = bf16(H1 @ W2^T) padded to 64 cols -> xm (dead)
  spmm_gemm128<false><<<MB32, 128, 0, stream>>>(rdA, bins2A, bufA, nullptr, Wb1, sc1, sh1,
                                                W2hi, W2lo, G2, N);

  // out = log_softmax(spmm(adj, G2) + b2)
  spmm_softmax64<<<RB, 256, 0, stream>>>(rdA, bins2A, G2, b2, out, N);
}

// Round 7
// 507.000 us; speedup vs baseline: 1.0514x; 1.0514x over previous
//
#include <hip/hip_runtime.h>
#include <math.h>

#define NFEAT 128
#define NCLS 40
#define NCLSP 64      // padded class dim (bf16) for pow2 lane math
#define BINROWS 64    // rows per bin
#define NBINMAX 1600  // >= ceil(100000/64)=1563
#define NBLKC 256     // chunks for the binning sort
#define CHUNKMAX 6400 // >= ceil(1600000/256)=6250 ; LDS stage = 50KB
#define SEGC 7        // ceil(NBINMAX/256)
#define RSMAX 2048    // per-bin capacity in bins2 (fixed stride) + row_sort LDS stage

typedef short bf16x8 __attribute__((ext_vector_type(8)));
typedef float f32x4 __attribute__((ext_vector_type(4)));

// ---------- bf16 helpers ----------
__device__ __forceinline__ float bf2f(unsigned int lo16) {
  return __uint_as_float((lo16 & 0xffffu) << 16);
}
__device__ __forceinline__ unsigned int f2bf(float x) {  // round-to-nearest-even
  unsigned int u = __float_as_uint(x);
  return (u + 0x7fffu + ((u >> 16) & 1u)) >> 16;
}

// ============================ merged prep: BN fold + W conv + x*M conv ============================
// block 0: BN fold; blocks 1..20: W0/W1 bf16 + W2 hi/lo split; blocks 21..: x*M -> bf16.
__global__ __launch_bounds__(256) void prep_all(
    const float* b0, const float* g0, const float* be0,
    const float* rm0, const float* rv0,
    const float* b1, const float* g1, const float* be1,
    const float* rm1, const float* rv1,
    float* sc0, float* sh0, float* sc1, float* sh1,
    const float* __restrict__ W0, const float* __restrict__ W1,
    const float* __restrict__ W2,
    unsigned short* __restrict__ Wb0, unsigned short* __restrict__ Wb1,
    unsigned short* __restrict__ W2hi, unsigned short* __restrict__ W2lo,
    const float* __restrict__ x, const float* __restrict__ Mv,
    unsigned short* __restrict__ xm, int n) {
  int t = threadIdx.x;
  if (blockIdx.x == 0) {
    if (t < 128) {
      float s = g0[t] * rsqrtf(rv0[t] + 1e-5f);
      sc0[t] = s;
      sh0[t] = (b0[t] - rm0[t]) * s + be0[t];
    } else {
      int i = t - 128;
      float s = g1[i] * rsqrtf(rv1[i] + 1e-5f);
      sc1[i] = s;
      sh1[i] = (b1[i] - rm1[i]) * s + be1[i];
    }
    return;
  }
  if (blockIdx.x <= 20) {
    int i = (blockIdx.x - 1) * 256 + t;  // 5120 threads, 8 elems each
    if (i < 4096) {
      const float* W = (i < 2048) ? W0 : W1;
      unsigned short* Wb = (i < 2048) ? Wb0 : Wb1;
      int j = (i < 2048) ? i : i - 2048;
      const float4* p = (const float4*)(W + (size_t)j * 8);
      float4 v0 = p[0], v1 = p[1];
      unsigned int o0 = f2bf(v0.x) | (f2bf(v0.y) << 16);
      unsigned int o1 = f2bf(v0.z) | (f2bf(v0.w) << 16);
      unsigned int o2 = f2bf(v1.x) | (f2bf(v1.y) << 16);
      unsigned int o3 = f2bf(v1.z) | (f2bf(v1.w) << 16);
      ((uint4*)Wb)[j] = make_uint4(o0, o1, o2, o3);
    } else {
      int j = i - 4096;  // chunk of 8 within padded 64x128
      int r = j >> 4;    // padded out-row
      float v[8] = {0.f, 0.f, 0.f, 0.f, 0.f, 0.f, 0.f, 0.f};
      if (r < NCLS) {  // j*8 == r*128 + (j&15)*8 exactly
        const float4* p = (const float4*)(W2 + (size_t)j * 8);
        float4 a = p[0], b = p[1];
        v[0] = a.x; v[1] = a.y; v[2] = a.z; v[3] = a.w;
        v[4] = b.x; v[5] = b.y; v[6] = b.z; v[7] = b.w;
      }
      unsigned int h[8], l[8];
#pragma unroll
      for (int q = 0; q < 8; ++q) {
        h[q] = f2bf(v[q]);
        l[q] = f2bf(v[q] - bf2f(h[q]));
      }
      ((uint4*)W2hi)[j] = make_uint4(h[0] | (h[1] << 16), h[2] | (h[3] << 16),
                                     h[4] | (h[5] << 16), h[6] | (h[7] << 16));
      ((uint4*)W2lo)[j] = make_uint4(l[0] | (l[1] << 16), l[2] | (l[3] << 16),
                                     l[4] | (l[5] << 16), l[6] | (l[7] << 16));
    }
    return;
  }
  int i = (blockIdx.x - 21) * 256 + t;  // one 8-elem chunk per thread
  if (i >= n * (NFEAT / 8)) return;
  int row = i >> 4;
  float m = Mv[row];
  const float4* p = (const float4*)(x + (size_t)i * 8);
  float4 v0 = p[0], v1 = p[1];
  unsigned int o0 = f2bf(v0.x * m) | (f2bf(v0.y * m) << 16);
  unsigned int o1 = f2bf(v0.z * m) | (f2bf(v0.w * m) << 16);
  unsigned int o2 = f2bf(v1.x * m) | (f2bf(v1.y * m) << 16);
  unsigned int o3 = f2bf(v1.z * m) | (f2bf(v1.w * m) << 16);
  ((uint4*)xm)[i] = make_uint4(o0, o1, o2, o3);
}

// ============================ stage 1 (merged Z+A): chunk -> 64-row bins ============================
// LDS staging is LOAD-BEARING: it converts the random-within-50KB scatter into
// linear full-cacheline global writes. Removing it (round 3) caused ~6x write
// amplification (WRITE_SIZE 26MB -> 144MB) and 2x kernel time. Do not remove.
__global__ __launch_bounds__(256) void bin_sort2(
    const int* __restrict__ srcZ, const int* __restrict__ dstZ, const float* __restrict__ valZ,
    const int* __restrict__ srcA, const int* __restrict__ dstA, const float* __restrict__ valA,
    int2* __restrict__ DrmZ, int2* __restrict__ DrmA,
    int2* __restrict__ binsCZ, int2* __restrict__ binsCA,
    int E, int nbin, int chunk) {
  __shared__ int2 stage[CHUNKMAX];
  __shared__ int cur[NBINMAX];
  __shared__ int ps[256];
  const int t = threadIdx.x;
  int k = blockIdx.x;
  const int* srcp; const int* dstp; const float* valp; int2* Drm; int2* binsC;
  if (k < NBLKC) {
    srcp = srcZ; dstp = dstZ; valp = valZ; Drm = DrmZ; binsC = binsCZ;
  } else {
    k -= NBLKC;
    srcp = srcA; dstp = dstA; valp = valA; Drm = DrmA; binsC = binsCA;
  }
  for (int i = t; i < nbin; i += 256) cur[i] = 0;
  __syncthreads();
  const int e0 = k * chunk, e1 = min(E, e0 + chunk);
#pragma unroll 4
  for (int e = e0 + t; e < e1; e += 256) atomicAdd(&cur[dstp[e] >> 6], 1);
  __syncthreads();
  int loc[SEGC], cnt[SEGC];
  int s = 0;
#pragma unroll
  for (int j = 0; j < SEGC; ++j) {
    int i = t * SEGC + j;
    int v = (i < nbin) ? cur[i] : 0;
    loc[j] = s; cnt[j] = v;
    s += v;
  }
  ps[t] = s;
  __syncthreads();
  for (int o = 1; o < 256; o <<= 1) {
    int x = (t >= o) ? ps[t - o] : 0;
    __syncthreads();
    ps[t] += x;
    __syncthreads();
  }
  int ex = ps[t] - s;
#pragma unroll
  for (int j = 0; j < SEGC; ++j) {
    int i = t * SEGC + j;
    if (i < nbin) {
      int o = ex + loc[j];
      Drm[(size_t)k * nbin + i] = make_int2(e0 + o, cnt[j]);
      cur[i] = o;
    }
  }
  __syncthreads();
#pragma unroll 2
  for (int e = e0 + t; e < e1; e += 256) {
    int d = dstp[e];
    int p = atomicAdd(&cur[d >> 6], 1);
    stage[p] = make_int2(srcp[e] | ((d & 63) << 17), __float_as_int(valp[e]));
  }
  __syncthreads();
  const int n = e1 - e0;
  for (int i = t; i < n; i += 256) binsC[e0 + i] = stage[i];
}

// ============================ stage 2 (merged Z+A): bin -> full dst-row sort ============================
// bins2 layout: bin b occupies [b*RSMAX, b*RSMAX+cnt). rowdesc[row] = (start, deg).
// Run descriptors read DIRECTLY from chunk-major Drm (stride nbin*8B): each 64B
// line covers 8 neighboring bins -> L2/L3 reuse by neighbor blocks. This
// replaces the former transposeD2 kernel (one launch + 6.4MB write/read saved).
__global__ __launch_bounds__(256) void row_sort2(
    const int2* __restrict__ DrmZ, const int2* __restrict__ DrmA,
    const int2* __restrict__ binsCZ, const int2* __restrict__ binsCA,
    int2* __restrict__ bins2Z, int2* __restrict__ bins2A,
    int2* __restrict__ rdZ, int2* __restrict__ rdA, int n, int nbin) {
  __shared__ int2 stage[RSMAX];
  __shared__ int ps[256];
  __shared__ int rcnt[BINROWS];
  __shared__ int roff[BINROWS];
  int b = blockIdx.x;
  const int t = threadIdx.x;
  const int2* Drm; const int2* binsC; int2* bins2; int2* rowdesc;
  if (b < nbin) {
    Drm = DrmZ; binsC = binsCZ; bins2 = bins2Z; rowdesc = rdZ;
  } else {
    b -= nbin;
    Drm = DrmA; binsC = binsCA; bins2 = bins2A; rowdesc = rdA;
  }
  if (t < BINROWS) rcnt[t] = 0;
  int2 run = Drm[(size_t)t * nbin + b];  // strided read (was transposed Dbm)
  ps[t] = run.y;
  __syncthreads();
  for (int o = 1; o < 256; o <<= 1) {
    int x = (t >= o) ? ps[t - o] : 0;
    __syncthreads();
    ps[t] += x;
    __syncthreads();
  }
  int mystart = ps[t] - run.y;
  for (int j = 0; j < run.y; ++j) {
    int2 en = binsC[run.x + j];
    int idx = mystart + j;
    if (idx < RSMAX) stage[idx] = en;
    atomicAdd(&rcnt[(en.x >> 17) & 63], 1);
  }
  __syncthreads();
  const int bs = b * RSMAX;
  if (t < BINROWS) {  // wave 0 only: scan 64 row counts
    int c = rcnt[t];
    int s = c;
#pragma unroll
    for (int o = 1; o < 64; o <<= 1) {
      int v = __shfl_up(s, o);
      if (t >= o) s += v;
    }
    int excl = s - c;
    int row = b * BINROWS + t;
    if (row < n) rowdesc[row] = make_int2(bs + excl, c);
    roff[t] = excl;
  }
  __syncthreads();
  int total = min(ps[255], RSMAX);
  for (int i = t; i < total; i += 256) {
    int2 en = stage[i];
    int row = (en.x >> 17) & 63;
    int p = atomicAdd(&roff[row], 1);
    bins2[bs + p] = en;
  }
}

// ============================ SPMM (128 feats), row-sorted, no LDS ============================
// One wave per row; lane owns 4 consecutive feats (8B). Two 32-lane halves each
// gather a DIFFERENT edge per step (one full 256B X-row per edge), 4 steps
// unrolled -> 8 gathers in flight. Halves combined via shfl_xor(32).
// [SACRED: round-0 form. Two loop rewrites (r1, r2) and a 16-rows-per-wave
//  fusion (r6) all regressed -- performance comes from 100K independent waves
//  (one row per wave, ~184 gathers in flight per CU). Do not touch; do not
//  serialize rows into waves.]
template <bool SCALE>
__global__ __launch_bounds__(256) void spmm128_sorted(
    const int2* __restrict__ rowdesc, const int2* __restrict__ bins2,
    const unsigned short* __restrict__ X, const float* __restrict__ AM,
    unsigned short* __restrict__ Y, int n) {
  int row = (blockIdx.x * 256 + threadIdx.x) >> 6;
  int lane = threadIdx.x & 63;
  if (row >= n) return;
  int2 rd = rowdesc[row];
  int s = rd.x, d = rd.y;
  int half = lane >> 5, l32 = lane & 31;
  float s0 = 0.f, s1 = 0.f, s2 = 0.f, s3 = 0.f;
  for (int kb = 0; kb < d; kb += 64) {
    int rem = min(64, d - kb);
    int2 my = (lane < rem) ? bins2[s + kb + lane] : make_int2(0, 0);  // w==0 pads
    int myc = my.x & 0x1FFFF;
    float myw = __int_as_float(my.y);
    for (int k = 0; k < rem; k += 8) {
#pragma unroll
      for (int st = 0; st < 4; ++st) {
        int idx = k + 2 * st + half;  // <= 63; pad entries have w==0
        int c = __shfl(myc, idx);
        float wv = __shfl(myw, idx);
        uint2 pv = *(const uint2*)(X + (size_t)c * NFEAT + l32 * 4);
        s0 += wv * bf2f(pv.x);
        s1 += wv * bf2f(pv.x >> 16);
        s2 += wv * bf2f(pv.y);
        s3 += wv * bf2f(pv.y >> 16);
      }
    }
  }
  s0 += __shfl_xor(s0, 32); s1 += __shfl_xor(s1, 32);
  s2 += __shfl_xor(s2, 32); s3 += __shfl_xor(s3, 32);
  if (SCALE) {
    float am = AM[row];
    s0 *= am; s1 *= am; s2 *= am; s3 *= am;
  }
  unsigned int pk = half ? (f2bf(s2) | (f2bf(s3) << 16)) : (f2bf(s0) | (f2bf(s1) << 16));
  ((unsigned int*)Y)[(size_t)row * (NFEAT / 2) + l32 * 2 + half] = pk;
}

// ============================ MFMA GEMM 128x128 (+BN+ReLU), flat IO ============================
// FUSE_G2=false (layer 0): Out = relu(bn(Y@W^T)) as bf16.
// FUSE_G2=true  (layer 1): H1 = relu(bn(Y@W1^T)) stays on-chip (LDS transpose
// staging), then G2 = H1 @ W2pad^T (hi+lo bf16 split of fp32 W2) is written.
template <bool FUSE_G2>
__global__ __launch_bounds__(256) void gemm_mfma128(
    const unsigned short* __restrict__ Y, const unsigned short* __restrict__ Wb,
    const float* __restrict__ scale, const float* __restrict__ shift,
    unsigned short* __restrict__ Out,
    const unsigned short* __restrict__ Whi, const unsigned short* __restrict__ Wlo,
    unsigned short* __restrict__ G2, int M) {
  const int wave = threadIdx.x >> 6;
  const int lane = threadIdx.x & 63;
  const int quad = lane >> 4;
  const int l16 = lane & 15;
  const int arow = blockIdx.x * 64 + wave * 16 + l16;
  const bool rv = arow < M;

  f32x4 acc[8];
#pragma unroll
  for (int c = 0; c < 8; ++c) acc[c] = (f32x4){0.f, 0.f, 0.f, 0.f};

#pragma unroll
  for (int kc = 0; kc < 128; kc += 32) {
    bf16x8 a = rv ? *(const bf16x8*)(Y + (size_t)arow * 128 + kc + quad * 8)
                  : (bf16x8){0, 0, 0, 0, 0, 0, 0, 0};
#pragma unroll
    for (int c = 0; c < 8; ++c) {
      bf16x8 b = *(const bf16x8*)(Wb + (size_t)(c * 16 + l16) * 128 + kc + quad * 8);
      acc[c] = __builtin_amdgcn_mfma_f32_16x16x32_bf16(a, b, acc[c], 0, 0, 0);
    }
  }

  const int orow0 = blockIdx.x * 64 + wave * 16 + quad * 4;

  if constexpr (!FUSE_G2) {
#pragma unroll
    for (int c = 0; c < 8; ++c) {
      int col = c * 16 + l16;
      float sc = scale[col], sh = shift[col];
#pragma unroll
      for (int r = 0; r < 4; ++r) {
        int orow = orow0 + r;
        if (orow < M) {
          float v = fmaxf(acc[c][r] * sc + sh, 0.f);
          Out[(size_t)orow * 128 + col] = (unsigned short)f2bf(v);
        }
      }
    }
  } else {
    // stage H1 tile (64x128 bf16) in LDS; each wave only touches its own 16 rows
    // (rows partitioned by wave for both write and read), +8-short row pad for banks.
    __shared__ unsigned short Ht[64][136];
    const int lrow0 = wave * 16 + quad * 4;
#pragma unroll
    for (int c = 0; c < 8; ++c) {
      int col = c * 16 + l16;
      float sc = scale[col], sh = shift[col];
#pragma unroll
      for (int r = 0; r < 4; ++r) {
        float v = fmaxf(acc[c][r] * sc + sh, 0.f);
        Ht[lrow0 + r][col] = (unsigned short)f2bf(v);
      }
    }
    __syncthreads();
    bf16x8 af[4];
#pragma unroll
    for (int kc = 0; kc < 4; ++kc)
      af[kc] = *(const bf16x8*)(&Ht[wave * 16 + l16][kc * 32 + quad * 8]);
    f32x4 acc2[4];
#pragma unroll
    for (int c2 = 0; c2 < 4; ++c2) acc2[c2] = (f32x4){0.f, 0.f, 0.f, 0.f};
#pragma unroll
    for (int kc = 0; kc < 4; ++kc) {
#pragma unroll
      for (int c2 = 0; c2 < 4; ++c2) {
        bf16x8 bh = *(const bf16x8*)(Whi + (size_t)(c2 * 16 + l16) * 128 + kc * 32 + quad * 8);
        bf16x8 bl = *(const bf16x8*)(Wlo + (size_t)(c2 * 16 + l16) * 128 + kc * 32 + quad * 8);
        acc2[c2] = __builtin_amdgcn_mfma_f32_16x16x32_bf16(af[kc], bh, acc2[c2], 0, 0, 0);
        acc2[c2] = __builtin_amdgcn_mfma_f32_16x16x32_bf16(af[kc], bl, acc2[c2], 0, 0, 0);
      }
    }
#pragma unroll
    for (int c2 = 0; c2 < 4; ++c2) {
      int col = c2 * 16 + l16;
#pragma unroll
      for (int r = 0; r < 4; ++r) {
        int orow = orow0 + r;
        if (orow < M) G2[(size_t)orow * NCLSP + col] = (unsigned short)f2bf(acc2[c2][r]);
      }
    }
  }
}

// ============================ final: spmm(40) + bias + log_softmax ============================
__global__ __launch_bounds__(256) void spmm_softmax64(
    const int2* __restrict__ rowdesc, const int2* __restrict__ bins2,
    const unsigned short* __restrict__ G2, const float* __restrict__ b2,
    float* __restrict__ out, int n) {
  int row = (blockIdx.x * 256 + threadIdx.x) >> 6;
  int lane = threadIdx.x & 63;
  if (row >= n) return;
  const int eidx = lane >> 4, q = lane & 15;
  const bool vq = q < (NCLS / 4);  // 10 quartets cover the 40 real classes
  float4 bv = vq ? *(const float4*)(b2 + q * 4) : make_float4(0.f, 0.f, 0.f, 0.f);

  int2 rdv = rowdesc[row];
  int s0i = rdv.x, d = rdv.y;
  float a0 = 0.f, a1 = 0.f, a2 = 0.f, a3 = 0.f;
  for (int kb = 0; kb < d; kb += 64) {
    int rem = min(64, d - kb);
    int2 my = (lane < rem) ? bins2[s0i + kb + lane] : make_int2(0, 0);
    int myc = my.x & 0x1FFFF;
    float myw = __int_as_float(my.y);
    int steps = (rem + 3) >> 2;
#pragma unroll 4
    for (int st = 0; st < steps; ++st) {
      int idx = st * 4 + eidx;  // <= 63; pad entries have w==0
      int c = __shfl(myc, idx);
      float wv = __shfl(myw, idx);
      uint2 pv = *(const uint2*)(G2 + (size_t)c * NCLSP + q * 4);
      a0 += wv * bf2f(pv.x);
      a1 += wv * bf2f(pv.x >> 16);
      a2 += wv * bf2f(pv.y);
      a3 += wv * bf2f(pv.y >> 16);
    }
  }
  a0 += __shfl_xor(a0, 16); a1 += __shfl_xor(a1, 16);
  a2 += __shfl_xor(a2, 16); a3 += __shfl_xor(a3, 16);
  a0 += __shfl_xor(a0, 32); a1 += __shfl_xor(a1, 32);
  a2 += __shfl_xor(a2, 32); a3 += __shfl_xor(a3, 32);
  float z0 = a0 + bv.x, z1 = a1 + bv.y, z2 = a2 + bv.z, z3 = a3 + bv.w;
  bool par = (eidx == 0) && vq;
  float m = par ? fmaxf(fmaxf(z0, z1), fmaxf(z2, z3)) : -INFINITY;
#pragma unroll
  for (int o = 1; o < 64; o <<= 1) m = fmaxf(m, __shfl_xor(m, o));
  float ex = par ? (__expf(z0 - m) + __expf(z1 - m) + __expf(z2 - m) + __expf(z3 - m)) : 0.f;
#pragma unroll
  for (int o = 1; o < 64; o <<= 1) ex += __shfl_xor(ex, o);
  float lg = m + __logf(ex);
  if (par) {
    *(float4*)&out[(size_t)row * NCLS + q * 4] =
        make_float4(z0 - lg, z1 - lg, z2 - lg, z3 - lg);
  }
}

// ============================ launch ============================

extern "C" void kernel_launch(void* const* d_in, const int* in_sizes, int n_in,
                              void* d_out, int out_size, void* d_ws, size_t ws_size,
                              hipStream_t stream) {
  const float* x    = (const float*)d_in[0];
  const float* Mv   = (const float*)d_in[1];
  const float* AM   = (const float*)d_in[2];
  const int* srcZ   = (const int*)d_in[3];
  const int* dstZ   = (const int*)d_in[4];
  const float* valsZ= (const float*)d_in[5];
  const int* src    = (const int*)d_in[6];
  const int* dst    = (const int*)d_in[7];
  const float* vals = (const float*)d_in[8];
  const float* W0   = (const float*)d_in[9];
  const float* b0   = (const float*)d_in[10];
  const float* g0   = (const float*)d_in[11];
  const float* be0  = (const float*)d_in[12];
  const float* rm0  = (const float*)d_in[13];
  const float* rv0  = (const float*)d_in[14];
  const float* W1   = (const float*)d_in[15];
  const float* b1   = (const float*)d_in[16];
  const float* g1   = (const float*)d_in[17];
  const float* be1  = (const float*)d_in[18];
  const float* rm1  = (const float*)d_in[19];
  const float* rv1  = (const float*)d_in[20];
  const float* W2   = (const float*)d_in[21];
  const float* b2   = (const float*)d_in[22];
  float* out = (float*)d_out;

  const int N = in_sizes[1];  // M has shape (N,1)
  const int E = in_sizes[3];
  const int NBIN = (N + BINROWS - 1) / BINROWS;
  const int CHUNK = (E + NBLKC - 1) / NBLKC;  // 6250 <= CHUNKMAX

  char* w = (char*)d_ws;
  size_t off = 0;
  auto alloc = [&](size_t bytes) -> void* {
    void* p = w + off;
    off = (off + bytes + 255) & ~(size_t)255;
    return p;
  };
  const size_t bins2Bytes = (size_t)NBIN * RSMAX * 8;     // 25.6MB fixed-stride layout
  const size_t bufBytes = (size_t)N * NFEAT * 2;          // 25.6MB
  int2* binsCZ = (int2*)alloc((size_t)NBLKC * CHUNK * 8); // 12.8MB chunk-ordered stage (Z)
  int2* binsCA = (int2*)alloc((size_t)NBLKC * CHUNK * 8); // 12.8MB chunk-ordered stage (A)
  int2* bins2A = (int2*)alloc(bins2Bytes);                // lives to the end
  int2* rdZ = (int2*)alloc((size_t)N * 8);                // rowdesc (start,deg) Z
  int2* rdA = (int2*)alloc((size_t)N * 8);                // rowdesc (start,deg) A
  unsigned short* xm = (unsigned short*)alloc(bufBytes);  // 25.6MB
  unsigned short* bufA = (unsigned short*)alloc(bufBytes);                 // Drm -> Y0 -> Y1
  unsigned short* bufB = (unsigned short*)alloc(bins2Bytes > bufBytes ? bins2Bytes : bufBytes);
  float* sc0 = (float*)alloc(128 * 4);
  float* sh0 = (float*)alloc(128 * 4);
  float* sc1 = (float*)alloc(128 * 4);
  float* sh1 = (float*)alloc(128 * 4);
  unsigned short* Wb0 = (unsigned short*)alloc(128 * 128 * 2);
  unsigned short* Wb1 = (unsigned short*)alloc(128 * 128 * 2);
  unsigned short* W2hi = (unsigned short*)alloc(64 * 128 * 2);
  unsigned short* W2lo = (unsigned short*)alloc(64 * 128 * 2);
  // aliases:
  //  - DrmZ/DrmA (3.2MB each) live in bufA until row_sort2 done; spmmZ then
  //    writes Y0 into bufA.
  //  - bins2Z (25.6MB fixed-stride) lives in bufB until spmmZ consumes it
  //    (gemm0 then overwrites bufB with H0); G2 (N x 64 bf16 = 12.8MB) lives in
  //    bufB after H0 dies (fused gemm1 reads Y1 from bufA, writes G2 to bufB).
  const size_t drmBytes = (size_t)NBLKC * NBIN * 8;  // 3,201,024 (mult of 256)
  int2* DrmZ = (int2*)((char*)bufA + 0 * drmBytes);
  int2* DrmA = (int2*)((char*)bufA + 1 * drmBytes);
  int2* bins2Z = (int2*)bufB;
  unsigned short* G2 = bufB;

  const int RB = (N + 3) / 4;  // 4 rows (waves) per 256-thread block
  const int GB64 = (N + 63) / 64;
  const int CONVB = (N * (NFEAT / 8) + 255) / 256;

  prep_all<<<21 + CONVB, 256, 0, stream>>>(b0, g0, be0, rm0, rv0, b1, g1, be1, rm1, rv1,
                                           sc0, sh0, sc1, sh1, W0, W1, W2,
                                           Wb0, Wb1, W2hi, W2lo, x, Mv, xm, N);

  // --- both adjacencies: chunk-bin sort -> full row sort (merged launches) ---
  bin_sort2<<<2 * NBLKC, 256, 0, stream>>>(srcZ, dstZ, valsZ, src, dst, vals,
                                           DrmZ, DrmA, binsCZ, binsCA, E, NBIN, CHUNK);
  row_sort2<<<2 * NBIN, 256, 0, stream>>>(DrmZ, DrmA, binsCZ, binsCA,
                                          bins2Z, bins2A, rdZ, rdA, N, NBIN);

  // layer 0: Y0 = spmm(adjZ, M*x)*AM ; H0 = relu(bn(Y0 @ W0^T + b0))
  spmm128_sorted<true><<<RB, 256, 0, stream>>>(rdZ, bins2Z, xm, AM, bufA, N);
  gemm_mfma128<false><<<GB64, 256, 0, stream>>>(bufA, Wb0, sc0, sh0, bufB,
                                                nullptr, nullptr, nullptr, N);

  // layer 1+2: Y1 = spmm(adj, H0) ; fused: H1 = relu(bn(Y1 @ W1^T + b1)) on-chip,
  // G2 = bf16(H1 @ W2^T) padded to 64 cols written directly.
  spmm128_sorted<false><<<RB, 256, 0, stream>>>(rdA, bins2A, bufB,
                                                (const float*)nullptr, bufA, N);
  gemm_mfma128<true><<<GB64, 256, 0, stream>>>(bufA, Wb1, sc1, sh1, nullptr,
                                               W2hi, W2lo, G2, N);

  // out = log_softmax(spmm(adj, G2) + b2)
  spmm_softmax64<<<RB, 256, 0, stream>>>(rdA, bins2A, G2, b2, out, N);
}

// Round 8
// 505.086 us; speedup vs baseline: 1.0554x; 1.0038x over previous
//
#include <hip/hip_runtime.h>
#include <math.h>

#define NFEAT 128
#define NCLS 40
#define NCLSP 64      // padded class dim (bf16) for pow2 lane math
#define BINROWS 64    // rows per bin
#define NBINMAX 1600  // >= ceil(100000/64)=1563
#define NBLKC 256     // chunks for the binning sort
#define CHUNKMAX 6400 // >= ceil(1600000/256)=6250 ; LDS stage = 50KB
#define CEDGE 25      // CHUNKMAX/256: max edges per thread per chunk
#define SEGC 7        // ceil(NBINMAX/256)
#define RSMAX 2048    // per-bin capacity in bins2 (fixed stride) + row_sort LDS stage

typedef short bf16x8 __attribute__((ext_vector_type(8)));
typedef float f32x4 __attribute__((ext_vector_type(4)));

// ---------- bf16 helpers ----------
__device__ __forceinline__ float bf2f(unsigned int lo16) {
  return __uint_as_float((lo16 & 0xffffu) << 16);
}
__device__ __forceinline__ unsigned int f2bf(float x) {  // round-to-nearest-even
  unsigned int u = __float_as_uint(x);
  return (u + 0x7fffu + ((u >> 16) & 1u)) >> 16;
}

// ============================ merged prep: BN fold + W conv + x*M conv ============================
// block 0: BN fold; blocks 1..20: W0/W1 bf16 + W2 hi/lo split; blocks 21..: x*M -> bf16.
__global__ __launch_bounds__(256) void prep_all(
    const float* b0, const float* g0, const float* be0,
    const float* rm0, const float* rv0,
    const float* b1, const float* g1, const float* be1,
    const float* rm1, const float* rv1,
    float* sc0, float* sh0, float* sc1, float* sh1,
    const float* __restrict__ W0, const float* __restrict__ W1,
    const float* __restrict__ W2,
    unsigned short* __restrict__ Wb0, unsigned short* __restrict__ Wb1,
    unsigned short* __restrict__ W2hi, unsigned short* __restrict__ W2lo,
    const float* __restrict__ x, const float* __restrict__ Mv,
    unsigned short* __restrict__ xm, int n) {
  int t = threadIdx.x;
  if (blockIdx.x == 0) {
    if (t < 128) {
      float s = g0[t] * rsqrtf(rv0[t] + 1e-5f);
      sc0[t] = s;
      sh0[t] = (b0[t] - rm0[t]) * s + be0[t];
    } else {
      int i = t - 128;
      float s = g1[i] * rsqrtf(rv1[i] + 1e-5f);
      sc1[i] = s;
      sh1[i] = (b1[i] - rm1[i]) * s + be1[i];
    }
    return;
  }
  if (blockIdx.x <= 20) {
    int i = (blockIdx.x - 1) * 256 + t;  // 5120 threads, 8 elems each
    if (i < 4096) {
      const float* W = (i < 2048) ? W0 : W1;
      unsigned short* Wb = (i < 2048) ? Wb0 : Wb1;
      int j = (i < 2048) ? i : i - 2048;
      const float4* p = (const float4*)(W + (size_t)j * 8);
      float4 v0 = p[0], v1 = p[1];
      unsigned int o0 = f2bf(v0.x) | (f2bf(v0.y) << 16);
      unsigned int o1 = f2bf(v0.z) | (f2bf(v0.w) << 16);
      unsigned int o2 = f2bf(v1.x) | (f2bf(v1.y) << 16);
      unsigned int o3 = f2bf(v1.z) | (f2bf(v1.w) << 16);
      ((uint4*)Wb)[j] = make_uint4(o0, o1, o2, o3);
    } else {
      int j = i - 4096;  // chunk of 8 within padded 64x128
      int r = j >> 4;    // padded out-row
      float v[8] = {0.f, 0.f, 0.f, 0.f, 0.f, 0.f, 0.f, 0.f};
      if (r < NCLS) {  // j*8 == r*128 + (j&15)*8 exactly
        const float4* p = (const float4*)(W2 + (size_t)j * 8);
        float4 a = p[0], b = p[1];
        v[0] = a.x; v[1] = a.y; v[2] = a.z; v[3] = a.w;
        v[4] = b.x; v[5] = b.y; v[6] = b.z; v[7] = b.w;
      }
      unsigned int h[8], l[8];
#pragma unroll
      for (int q = 0; q < 8; ++q) {
        h[q] = f2bf(v[q]);
        l[q] = f2bf(v[q] - bf2f(h[q]));
      }
      ((uint4*)W2hi)[j] = make_uint4(h[0] | (h[1] << 16), h[2] | (h[3] << 16),
                                     h[4] | (h[5] << 16), h[6] | (h[7] << 16));
      ((uint4*)W2lo)[j] = make_uint4(l[0] | (l[1] << 16), l[2] | (l[3] << 16),
                                     l[4] | (l[5] << 16), l[6] | (l[7] << 16));
    }
    return;
  }
  int i = (blockIdx.x - 21) * 256 + t;  // one 8-elem chunk per thread
  if (i >= n * (NFEAT / 8)) return;
  int row = i >> 4;
  float m = Mv[row];
  const float4* p = (const float4*)(x + (size_t)i * 8);
  float4 v0 = p[0], v1 = p[1];
  unsigned int o0 = f2bf(v0.x * m) | (f2bf(v0.y * m) << 16);
  unsigned int o1 = f2bf(v0.z * m) | (f2bf(v0.w * m) << 16);
  unsigned int o2 = f2bf(v1.x * m) | (f2bf(v1.y * m) << 16);
  unsigned int o3 = f2bf(v1.z * m) | (f2bf(v1.w * m) << 16);
  ((uint4*)xm)[i] = make_uint4(o0, o1, o2, o3);
}

// ============================ stage 1 (merged Z+A): chunk -> 64-row bins ============================
// LDS staging is LOAD-BEARING: it converts the random-within-50KB scatter into
// linear full-cacheline global writes (round-3 lesson; removing it caused 6x
// write amplification). Single-atomic-pass: pass 1 captures each edge's rank
// from the counting atomicAdd (packed with bin + d&63 into a fully-unrolled
// register array); pass 2 places with a plain LDS read -- no second atomic, no
// second dst read.
__global__ __launch_bounds__(256) void bin_sort2(
    const int* __restrict__ srcZ, const int* __restrict__ dstZ, const float* __restrict__ valZ,
    const int* __restrict__ srcA, const int* __restrict__ dstA, const float* __restrict__ valA,
    int2* __restrict__ DrmZ, int2* __restrict__ DrmA,
    int2* __restrict__ binsCZ, int2* __restrict__ binsCA,
    int E, int nbin, int chunk) {
  __shared__ int2 stage[CHUNKMAX];
  __shared__ int cur[NBINMAX];
  __shared__ int ps[256];
  const int t = threadIdx.x;
  int k = blockIdx.x;
  const int* srcp; const int* dstp; const float* valp; int2* Drm; int2* binsC;
  if (k < NBLKC) {
    srcp = srcZ; dstp = dstZ; valp = valZ; Drm = DrmZ; binsC = binsCZ;
  } else {
    k -= NBLKC;
    srcp = srcA; dstp = dstA; valp = valA; Drm = DrmA; binsC = binsCA;
  }
  for (int i = t; i < nbin; i += 256) cur[i] = 0;
  __syncthreads();
  const int e0 = k * chunk, e1 = min(E, e0 + chunk);
  // pass 1: count + capture rank. pk = (bin<<19) | ((d&63)<<13) | rank
  // (bin < 2048: 11 bits; rank < 6400: 13 bits; d&63: 6 bits)
  int pk[CEDGE];
#pragma unroll
  for (int j = 0; j < CEDGE; ++j) {
    int e = e0 + t + j * 256;
    if (e < e1) {
      int d = dstp[e];
      int bin = d >> 6;
      int r = atomicAdd(&cur[bin], 1);
      pk[j] = (bin << 19) | ((d & 63) << 13) | r;
    }
  }
  __syncthreads();
  int loc[SEGC], cnt[SEGC];
  int s = 0;
#pragma unroll
  for (int j = 0; j < SEGC; ++j) {
    int i = t * SEGC + j;
    int v = (i < nbin) ? cur[i] : 0;
    loc[j] = s; cnt[j] = v;
    s += v;
  }
  ps[t] = s;
  __syncthreads();
  for (int o = 1; o < 256; o <<= 1) {
    int x = (t >= o) ? ps[t - o] : 0;
    __syncthreads();
    ps[t] += x;
    __syncthreads();
  }
  int ex = ps[t] - s;
#pragma unroll
  for (int j = 0; j < SEGC; ++j) {
    int i = t * SEGC + j;
    if (i < nbin) {
      int o = ex + loc[j];
      Drm[(size_t)k * nbin + i] = make_int2(e0 + o, cnt[j]);
      cur[i] = o;
    }
  }
  __syncthreads();
  // pass 2: place via base[bin] + rank (plain LDS read, no atomic)
#pragma unroll
  for (int j = 0; j < CEDGE; ++j) {
    int e = e0 + t + j * 256;
    if (e < e1) {
      int v = pk[j];
      int p = cur[(unsigned)v >> 19] + (v & 0x1FFF);
      stage[p] = make_int2(srcp[e] | (((v >> 13) & 63) << 17), __float_as_int(valp[e]));
    }
  }
  __syncthreads();
  const int n = e1 - e0;
  for (int i = t; i < n; i += 256) binsC[e0 + i] = stage[i];
}

// ============================ stage 2 (merged Z+A): bin -> full dst-row sort ============================
// bins2 layout: bin b occupies [b*RSMAX, b*RSMAX+cnt). rowdesc[row] = (start, deg).
// Run descriptors read DIRECTLY from chunk-major Drm (stride nbin*8B; 64B line
// covers 8 neighbor bins -> L2/L3 reuse). Gather pass captures each edge's
// row-rank from the counting atomicAdd; scatter pass is atomic-free.
__global__ __launch_bounds__(256) void row_sort2(
    const int2* __restrict__ DrmZ, const int2* __restrict__ DrmA,
    const int2* __restrict__ binsCZ, const int2* __restrict__ binsCA,
    int2* __restrict__ bins2Z, int2* __restrict__ bins2A,
    int2* __restrict__ rdZ, int2* __restrict__ rdA, int n, int nbin) {
  __shared__ int2 stage[RSMAX];
  __shared__ short rankArr[RSMAX];
  __shared__ int ps[256];
  __shared__ int rcnt[BINROWS];
  __shared__ int roff[BINROWS];
  int b = blockIdx.x;
  const int t = threadIdx.x;
  const int2* Drm; const int2* binsC; int2* bins2; int2* rowdesc;
  if (b < nbin) {
    Drm = DrmZ; binsC = binsCZ; bins2 = bins2Z; rowdesc = rdZ;
  } else {
    b -= nbin;
    Drm = DrmA; binsC = binsCA; bins2 = bins2A; rowdesc = rdA;
  }
  if (t < BINROWS) rcnt[t] = 0;
  int2 run = Drm[(size_t)t * nbin + b];  // strided read (chunk-major)
  ps[t] = run.y;
  __syncthreads();
  for (int o = 1; o < 256; o <<= 1) {
    int x = (t >= o) ? ps[t - o] : 0;
    __syncthreads();
    ps[t] += x;
    __syncthreads();
  }
  int mystart = ps[t] - run.y;
  for (int j = 0; j < run.y; ++j) {
    int2 en = binsC[run.x + j];
    int idx = mystart + j;
    int r = atomicAdd(&rcnt[(en.x >> 17) & 63], 1);
    if (idx < RSMAX) {
      stage[idx] = en;
      rankArr[idx] = (short)r;
    }
  }
  __syncthreads();
  const int bs = b * RSMAX;
  if (t < BINROWS) {  // wave 0 only: scan 64 row counts
    int c = rcnt[t];
    int s = c;
#pragma unroll
    for (int o = 1; o < 64; o <<= 1) {
      int v = __shfl_up(s, o);
      if (t >= o) s += v;
    }
    int excl = s - c;
    int row = b * BINROWS + t;
    if (row < n) rowdesc[row] = make_int2(bs + excl, c);
    roff[t] = excl;
  }
  __syncthreads();
  int total = min(ps[255], RSMAX);
  for (int i = t; i < total; i += 256) {
    int2 en = stage[i];
    int row = (en.x >> 17) & 63;
    bins2[bs + roff[row] + rankArr[i]] = en;  // atomic-free scatter
  }
}

// ============================ SPMM (128 feats), row-sorted, no LDS ============================
// One wave per row; lane owns 4 consecutive feats (8B). Two 32-lane halves each
// gather a DIFFERENT edge per step (one full 256B X-row per edge), 4 steps
// unrolled -> 8 gathers in flight. Halves combined via shfl_xor(32).
// [SACRED inner body: round-0 form. Two loop rewrites (r1, r2) and a
//  16-rows-per-wave fusion (r6) all regressed -- performance comes from 100K
//  independent waves. 128-thread blocks (r8): finer block retirement reduces
//  the slow-row straggler tail; body untouched.]
template <bool SCALE>
__global__ __launch_bounds__(128) void spmm128_sorted(
    const int2* __restrict__ rowdesc, const int2* __restrict__ bins2,
    const unsigned short* __restrict__ X, const float* __restrict__ AM,
    unsigned short* __restrict__ Y, int n) {
  int row = (blockIdx.x * 128 + threadIdx.x) >> 6;
  int lane = threadIdx.x & 63;
  if (row >= n) return;
  int2 rd = rowdesc[row];
  int s = rd.x, d = rd.y;
  int half = lane >> 5, l32 = lane & 31;
  float s0 = 0.f, s1 = 0.f, s2 = 0.f, s3 = 0.f;
  for (int kb = 0; kb < d; kb += 64) {
    int rem = min(64, d - kb);
    int2 my = (lane < rem) ? bins2[s + kb + lane] : make_int2(0, 0);  // w==0 pads
    int myc = my.x & 0x1FFFF;
    float myw = __int_as_float(my.y);
    for (int k = 0; k < rem; k += 8) {
#pragma unroll
      for (int st = 0; st < 4; ++st) {
        int idx = k + 2 * st + half;  // <= 63; pad entries have w==0
        int c = __shfl(myc, idx);
        float wv = __shfl(myw, idx);
        uint2 pv = *(const uint2*)(X + (size_t)c * NFEAT + l32 * 4);
        s0 += wv * bf2f(pv.x);
        s1 += wv * bf2f(pv.x >> 16);
        s2 += wv * bf2f(pv.y);
        s3 += wv * bf2f(pv.y >> 16);
      }
    }
  }
  s0 += __shfl_xor(s0, 32); s1 += __shfl_xor(s1, 32);
  s2 += __shfl_xor(s2, 32); s3 += __shfl_xor(s3, 32);
  if (SCALE) {
    float am = AM[row];
    s0 *= am; s1 *= am; s2 *= am; s3 *= am;
  }
  unsigned int pk = half ? (f2bf(s2) | (f2bf(s3) << 16)) : (f2bf(s0) | (f2bf(s1) << 16));
  ((unsigned int*)Y)[(size_t)row * (NFEAT / 2) + l32 * 2 + half] = pk;
}

// ============================ MFMA GEMM 128x128 (+BN+ReLU), flat IO ============================
// FUSE_G2=false (layer 0): Out = relu(bn(Y@W^T)) as bf16.
// FUSE_G2=true  (layer 1): H1 = relu(bn(Y@W1^T)) stays on-chip (LDS transpose
// staging), then G2 = H1 @ W2pad^T (hi+lo bf16 split of fp32 W2) is written.
template <bool FUSE_G2>
__global__ __launch_bounds__(256) void gemm_mfma128(
    const unsigned short* __restrict__ Y, const unsigned short* __restrict__ Wb,
    const float* __restrict__ scale, const float* __restrict__ shift,
    unsigned short* __restrict__ Out,
    const unsigned short* __restrict__ Whi, const unsigned short* __restrict__ Wlo,
    unsigned short* __restrict__ G2, int M) {
  const int wave = threadIdx.x >> 6;
  const int lane = threadIdx.x & 63;
  const int quad = lane >> 4;
  const int l16 = lane & 15;
  const int arow = blockIdx.x * 64 + wave * 16 + l16;
  const bool rv = arow < M;

  f32x4 acc[8];
#pragma unroll
  for (int c = 0; c < 8; ++c) acc[c] = (f32x4){0.f, 0.f, 0.f, 0.f};

#pragma unroll
  for (int kc = 0; kc < 128; kc += 32) {
    bf16x8 a = rv ? *(const bf16x8*)(Y + (size_t)arow * 128 + kc + quad * 8)
                  : (bf16x8){0, 0, 0, 0, 0, 0, 0, 0};
#pragma unroll
    for (int c = 0; c < 8; ++c) {
      bf16x8 b = *(const bf16x8*)(Wb + (size_t)(c * 16 + l16) * 128 + kc + quad * 8);
      acc[c] = __builtin_amdgcn_mfma_f32_16x16x32_bf16(a, b, acc[c], 0, 0, 0);
    }
  }

  const int orow0 = blockIdx.x * 64 + wave * 16 + quad * 4;

  if constexpr (!FUSE_G2) {
#pragma unroll
    for (int c = 0; c < 8; ++c) {
      int col = c * 16 + l16;
      float sc = scale[col], sh = shift[col];
#pragma unroll
      for (int r = 0; r < 4; ++r) {
        int orow = orow0 + r;
        if (orow < M) {
          float v = fmaxf(acc[c][r] * sc + sh, 0.f);
          Out[(size_t)orow * 128 + col] = (unsigned short)f2bf(v);
        }
      }
    }
  } else {
    // stage H1 tile (64x128 bf16) in LDS; each wave only touches its own 16 rows
    // (rows partitioned by wave for both write and read), +8-short row pad for banks.
    __shared__ unsigned short Ht[64][136];
    const int lrow0 = wave * 16 + quad * 4;
#pragma unroll
    for (int c = 0; c < 8; ++c) {
      int col = c * 16 + l16;
      float sc = scale[col], sh = shift[col];
#pragma unroll
      for (int r = 0; r < 4; ++r) {
        float v = fmaxf(acc[c][r] * sc + sh, 0.f);
        Ht[lrow0 + r][col] = (unsigned short)f2bf(v);
      }
    }
    __syncthreads();
    bf16x8 af[4];
#pragma unroll
    for (int kc = 0; kc < 4; ++kc)
      af[kc] = *(const bf16x8*)(&Ht[wave * 16 + l16][kc * 32 + quad * 8]);
    f32x4 acc2[4];
#pragma unroll
    for (int c2 = 0; c2 < 4; ++c2) acc2[c2] = (f32x4){0.f, 0.f, 0.f, 0.f};
#pragma unroll
    for (int kc = 0; kc < 4; ++kc) {
#pragma unroll
      for (int c2 = 0; c2 < 4; ++c2) {
        bf16x8 bh = *(const bf16x8*)(Whi + (size_t)(c2 * 16 + l16) * 128 + kc * 32 + quad * 8);
        bf16x8 bl = *(const bf16x8*)(Wlo + (size_t)(c2 * 16 + l16) * 128 + kc * 32 + quad * 8);
        acc2[c2] = __builtin_amdgcn_mfma_f32_16x16x32_bf16(af[kc], bh, acc2[c2], 0, 0, 0);
        acc2[c2] = __builtin_amdgcn_mfma_f32_16x16x32_bf16(af[kc], bl, acc2[c2], 0, 0, 0);
      }
    }
#pragma unroll
    for (int c2 = 0; c2 < 4; ++c2) {
      int col = c2 * 16 + l16;
#pragma unroll
      for (int r = 0; r < 4; ++r) {
        int orow = orow0 + r;
        if (orow < M) G2[(size_t)orow * NCLSP + col] = (unsigned short)f2bf(acc2[c2][r]);
      }
    }
  }
}

// ============================ final: spmm(40) + bias + log_softmax ============================
__global__ __launch_bounds__(128) void spmm_softmax64(
    const int2* __restrict__ rowdesc, const int2* __restrict__ bins2,
    const unsigned short* __restrict__ G2, const float* __restrict__ b2,
    float* __restrict__ out, int n) {
  int row = (blockIdx.x * 128 + threadIdx.x) >> 6;
  int lane = threadIdx.x & 63;
  if (row >= n) return;
  const int eidx = lane >> 4, q = lane & 15;
  const bool vq = q < (NCLS / 4);  // 10 quartets cover the 40 real classes
  float4 bv = vq ? *(const float4*)(b2 + q * 4) : make_float4(0.f, 0.f, 0.f, 0.f);

  int2 rdv = rowdesc[row];
  int s0i = rdv.x, d = rdv.y;
  float a0 = 0.f, a1 = 0.f, a2 = 0.f, a3 = 0.f;
  for (int kb = 0; kb < d; kb += 64) {
    int rem = min(64, d - kb);
    int2 my = (lane < rem) ? bins2[s0i + kb + lane] : make_int2(0, 0);
    int myc = my.x & 0x1FFFF;
    float myw = __int_as_float(my.y);
    int steps = (rem + 3) >> 2;
#pragma unroll 4
    for (int st = 0; st < steps; ++st) {
      int idx = st * 4 + eidx;  // <= 63; pad entries have w==0
      int c = __shfl(myc, idx);
      float wv = __shfl(myw, idx);
      uint2 pv = *(const uint2*)(G2 + (size_t)c * NCLSP + q * 4);
      a0 += wv * bf2f(pv.x);
      a1 += wv * bf2f(pv.x >> 16);
      a2 += wv * bf2f(pv.y);
      a3 += wv * bf2f(pv.y >> 16);
    }
  }
  a0 += __shfl_xor(a0, 16); a1 += __shfl_xor(a1, 16);
  a2 += __shfl_xor(a2, 16); a3 += __shfl_xor(a3, 16);
  a0 += __shfl_xor(a0, 32); a1 += __shfl_xor(a1, 32);
  a2 += __shfl_xor(a2, 32); a3 += __shfl_xor(a3, 32);
  float z0 = a0 + bv.x, z1 = a1 + bv.y, z2 = a2 + bv.z, z3 = a3 + bv.w;
  bool par = (eidx == 0) && vq;
  float m = par ? fmaxf(fmaxf(z0, z1), fmaxf(z2, z3)) : -INFINITY;
#pragma unroll
  for (int o = 1; o < 64; o <<= 1) m = fmaxf(m, __shfl_xor(m, o));
  float ex = par ? (__expf(z0 - m) + __expf(z1 - m) + __expf(z2 - m) + __expf(z3 - m)) : 0.f;
#pragma unroll
  for (int o = 1; o < 64; o <<= 1) ex += __shfl_xor(ex, o);
  float lg = m + __logf(ex);
  if (par) {
    *(float4*)&out[(size_t)row * NCLS + q * 4] =
        make_float4(z0 - lg, z1 - lg, z2 - lg, z3 - lg);
  }
}

// ============================ launch ============================

extern "C" void kernel_launch(void* const* d_in, const int* in_sizes, int n_in,
                              void* d_out, int out_size, void* d_ws, size_t ws_size,
                              hipStream_t stream) {
  const float* x    = (const float*)d_in[0];
  const float* Mv   = (const float*)d_in[1];
  const float* AM   = (const float*)d_in[2];
  const int* srcZ   = (const int*)d_in[3];
  const int* dstZ   = (const int*)d_in[4];
  const float* valsZ= (const float*)d_in[5];
  const int* src    = (const int*)d_in[6];
  const int* dst    = (const int*)d_in[7];
  const float* vals = (const float*)d_in[8];
  const float* W0   = (const float*)d_in[9];
  const float* b0   = (const float*)d_in[10];
  const float* g0   = (const float*)d_in[11];
  const float* be0  = (const float*)d_in[12];
  const float* rm0  = (const float*)d_in[13];
  const float* rv0  = (const float*)d_in[14];
  const float* W1   = (const float*)d_in[15];
  const float* b1   = (const float*)d_in[16];
  const float* g1   = (const float*)d_in[17];
  const float* be1  = (const float*)d_in[18];
  const float* rm1  = (const float*)d_in[19];
  const float* rv1  = (const float*)d_in[20];
  const float* W2   = (const float*)d_in[21];
  const float* b2   = (const float*)d_in[22];
  float* out = (float*)d_out;

  const int N = in_sizes[1];  // M has shape (N,1)
  const int E = in_sizes[3];
  const int NBIN = (N + BINROWS - 1) / BINROWS;
  const int CHUNK = (E + NBLKC - 1) / NBLKC;  // 6250 <= CHUNKMAX

  char* w = (char*)d_ws;
  size_t off = 0;
  auto alloc = [&](size_t bytes) -> void* {
    void* p = w + off;
    off = (off + bytes + 255) & ~(size_t)255;
    return p;
  };
  const size_t bins2Bytes = (size_t)NBIN * RSMAX * 8;     // 25.6MB fixed-stride layout
  const size_t bufBytes = (size_t)N * NFEAT * 2;          // 25.6MB
  int2* binsCZ = (int2*)alloc((size_t)NBLKC * CHUNK * 8); // 12.8MB chunk-ordered stage (Z)
  int2* binsCA = (int2*)alloc((size_t)NBLKC * CHUNK * 8); // 12.8MB chunk-ordered stage (A)
  int2* bins2A = (int2*)alloc(bins2Bytes);                // lives to the end
  int2* rdZ = (int2*)alloc((size_t)N * 8);                // rowdesc (start,deg) Z
  int2* rdA = (int2*)alloc((size_t)N * 8);                // rowdesc (start,deg) A
  unsigned short* xm = (unsigned short*)alloc(bufBytes);  // 25.6MB
  unsigned short* bufA = (unsigned short*)alloc(bufBytes);                 // Drm -> Y0 -> Y1
  unsigned short* bufB = (unsigned short*)alloc(bins2Bytes > bufBytes ? bins2Bytes : bufBytes);
  float* sc0 = (float*)alloc(128 * 4);
  float* sh0 = (float*)alloc(128 * 4);
  float* sc1 = (float*)alloc(128 * 4);
  float* sh1 = (float*)alloc(128 * 4);
  unsigned short* Wb0 = (unsigned short*)alloc(128 * 128 * 2);
  unsigned short* Wb1 = (unsigned short*)alloc(128 * 128 * 2);
  unsigned short* W2hi = (unsigned short*)alloc(64 * 128 * 2);
  unsigned short* W2lo = (unsigned short*)alloc(64 * 128 * 2);
  // aliases:
  //  - DrmZ/DrmA (3.2MB each) live in bufA until row_sort2 done; spmmZ then
  //    writes Y0 into bufA.
  //  - bins2Z (25.6MB fixed-stride) lives in bufB until spmmZ consumes it
  //    (gemm0 then overwrites bufB with H0); G2 (N x 64 bf16 = 12.8MB) lives in
  //    bufB after H0 dies (fused gemm1 reads Y1 from bufA, writes G2 to bufB).
  const size_t drmBytes = (size_t)NBLKC * NBIN * 8;  // 3,201,024 (mult of 256)
  int2* DrmZ = (int2*)((char*)bufA + 0 * drmBytes);
  int2* DrmA = (int2*)((char*)bufA + 1 * drmBytes);
  int2* bins2Z = (int2*)bufB;
  unsigned short* G2 = bufB;

  const int RB2 = (N + 1) / 2;  // 2 rows (waves) per 128-thread block
  const int GB64 = (N + 63) / 64;
  const int CONVB = (N * (NFEAT / 8) + 255) / 256;

  prep_all<<<21 + CONVB, 256, 0, stream>>>(b0, g0, be0, rm0, rv0, b1, g1, be1, rm1, rv1,
                                           sc0, sh0, sc1, sh1, W0, W1, W2,
                                           Wb0, Wb1, W2hi, W2lo, x, Mv, xm, N);

  // --- both adjacencies: chunk-bin sort -> full row sort (merged launches) ---
  bin_sort2<<<2 * NBLKC, 256, 0, stream>>>(srcZ, dstZ, valsZ, src, dst, vals,
                                           DrmZ, DrmA, binsCZ, binsCA, E, NBIN, CHUNK);
  row_sort2<<<2 * NBIN, 256, 0, stream>>>(DrmZ, DrmA, binsCZ, binsCA,
                                          bins2Z, bins2A, rdZ, rdA, N, NBIN);

  // layer 0: Y0 = spmm(adjZ, M*x)*AM ; H0 = relu(bn(Y0 @ W0^T + b0))
  spmm128_sorted<true><<<RB2, 128, 0, stream>>>(rdZ, bins2Z, xm, AM, bufA, N);
  gemm_mfma128<false><<<GB64, 256, 0, stream>>>(bufA, Wb0, sc0, sh0, bufB,
                                                nullptr, nullptr, nullptr, N);

  // layer 1+2: Y1 = spmm(adj, H0) ; fused: H1 = relu(bn(Y1 @ W1^T + b1)) on-chip,
  // G2 = bf16(H1 @ W2^T) padded to 64 cols written directly.
  spmm128_sorted<false><<<RB2, 128, 0, stream>>>(rdA, bins2A, bufB,
                                                 (const float*)nullptr, bufA, N);
  gemm_mfma128<true><<<GB64, 256, 0, stream>>>(bufA, Wb1, sc1, sh1, nullptr,
                                               W2hi, W2lo, G2, N);

  // out = log_softmax(spmm(adj, G2) + b2)
  spmm_softmax64<<<RB2, 128, 0, stream>>>(rdA, bins2A, G2, b2, out, N);
}

// Round 9
// 494.235 us; speedup vs baseline: 1.0786x; 1.0220x over previous
//
#include <hip/hip_runtime.h>
#include <math.h>

#define NFEAT 128
#define NCLS 40
#define NCLSP 64      // padded class dim (bf16) for pow2 lane math
#define BINROWS 64    // rows per bin
#define NBINMAX 1600  // >= ceil(100000/64)=1563
#define NBLKC 256     // chunks for the binning sort
#define CHUNKMAX 6400 // >= ceil(1600000/256)=6250
#define STHALF 3200   // half-chunk LDS stage (>= ceil(6250/2)=3125); 25.6KB
#define CEDGE 25      // CHUNKMAX/256: max edges per thread per chunk
#define SEGC 7        // ceil(NBINMAX/256)
#define RSMAX 2048    // per-bin capacity in bins2 (fixed stride) + row_sort LDS stage

typedef short bf16x8 __attribute__((ext_vector_type(8)));
typedef float f32x4 __attribute__((ext_vector_type(4)));

// ---------- bf16 helpers ----------
__device__ __forceinline__ float bf2f(unsigned int lo16) {
  return __uint_as_float((lo16 & 0xffffu) << 16);
}
__device__ __forceinline__ unsigned int f2bf(float x) {  // round-to-nearest-even
  unsigned int u = __float_as_uint(x);
  return (u + 0x7fffu + ((u >> 16) & 1u)) >> 16;
}

// ============================ merged prep: BN fold + W conv + x*M conv ============================
__global__ __launch_bounds__(256) void prep_all(
    const float* b0, const float* g0, const float* be0,
    const float* rm0, const float* rv0,
    const float* b1, const float* g1, const float* be1,
    const float* rm1, const float* rv1,
    float* sc0, float* sh0, float* sc1, float* sh1,
    const float* __restrict__ W0, const float* __restrict__ W1,
    const float* __restrict__ W2,
    unsigned short* __restrict__ Wb0, unsigned short* __restrict__ Wb1,
    unsigned short* __restrict__ W2hi, unsigned short* __restrict__ W2lo,
    const float* __restrict__ x, const float* __restrict__ Mv,
    unsigned short* __restrict__ xm, int n) {
  int t = threadIdx.x;
  if (blockIdx.x == 0) {
    if (t < 128) {
      float s = g0[t] * rsqrtf(rv0[t] + 1e-5f);
      sc0[t] = s;
      sh0[t] = (b0[t] - rm0[t]) * s + be0[t];
    } else {
      int i = t - 128;
      float s = g1[i] * rsqrtf(rv1[i] + 1e-5f);
      sc1[i] = s;
      sh1[i] = (b1[i] - rm1[i]) * s + be1[i];
    }
    return;
  }
  if (blockIdx.x <= 20) {
    int i = (blockIdx.x - 1) * 256 + t;  // 5120 threads, 8 elems each
    if (i < 4096) {
      const float* W = (i < 2048) ? W0 : W1;
      unsigned short* Wb = (i < 2048) ? Wb0 : Wb1;
      int j = (i < 2048) ? i : i - 2048;
      const float4* p = (const float4*)(W + (size_t)j * 8);
      float4 v0 = p[0], v1 = p[1];
      unsigned int o0 = f2bf(v0.x) | (f2bf(v0.y) << 16);
      unsigned int o1 = f2bf(v0.z) | (f2bf(v0.w) << 16);
      unsigned int o2 = f2bf(v1.x) | (f2bf(v1.y) << 16);
      unsigned int o3 = f2bf(v1.z) | (f2bf(v1.w) << 16);
      ((uint4*)Wb)[j] = make_uint4(o0, o1, o2, o3);
    } else {
      int j = i - 4096;  // chunk of 8 within padded 64x128
      int r = j >> 4;    // padded out-row
      float v[8] = {0.f, 0.f, 0.f, 0.f, 0.f, 0.f, 0.f, 0.f};
      if (r < NCLS) {  // j*8 == r*128 + (j&15)*8 exactly
        const float4* p = (const float4*)(W2 + (size_t)j * 8);
        float4 a = p[0], b = p[1];
        v[0] = a.x; v[1] = a.y; v[2] = a.z; v[3] = a.w;
        v[4] = b.x; v[5] = b.y; v[6] = b.z; v[7] = b.w;
      }
      unsigned int h[8], l[8];
#pragma unroll
      for (int q = 0; q < 8; ++q) {
        h[q] = f2bf(v[q]);
        l[q] = f2bf(v[q] - bf2f(h[q]));
      }
      ((uint4*)W2hi)[j] = make_uint4(h[0] | (h[1] << 16), h[2] | (h[3] << 16),
                                     h[4] | (h[5] << 16), h[6] | (h[7] << 16));
      ((uint4*)W2lo)[j] = make_uint4(l[0] | (l[1] << 16), l[2] | (l[3] << 16),
                                     l[4] | (l[5] << 16), l[6] | (l[7] << 16));
    }
    return;
  }
  int i = (blockIdx.x - 21) * 256 + t;  // one 8-elem chunk per thread
  if (i >= n * (NFEAT / 8)) return;
  int row = i >> 4;
  float m = Mv[row];
  const float4* p = (const float4*)(x + (size_t)i * 8);
  float4 v0 = p[0], v1 = p[1];
  unsigned int o0 = f2bf(v0.x * m) | (f2bf(v0.y * m) << 16);
  unsigned int o1 = f2bf(v0.z * m) | (f2bf(v0.w * m) << 16);
  unsigned int o2 = f2bf(v1.x * m) | (f2bf(v1.y * m) << 16);
  unsigned int o3 = f2bf(v1.z * m) | (f2bf(v1.w * m) << 16);
  ((uint4*)xm)[i] = make_uint4(o0, o1, o2, o3);
}

// ============================ stage 1 (merged Z+A): chunk -> 64-row bins ============================
// LDS staging is LOAD-BEARING (round-3 lesson: removing it -> 6x write
// amplification). r9: placement/flush split into TWO half-chunk passes through
// a 25.6KB stage -> LDS 57KB->33KB -> 4 blocks/CU (was 2), doubling
// latency-hiding for the linear loads. Rank cached in registers (r8), so the
// second pass costs no atomics and no extra global reads.
__global__ __launch_bounds__(256) void bin_sort2(
    const int* __restrict__ srcZ, const int* __restrict__ dstZ, const float* __restrict__ valZ,
    const int* __restrict__ srcA, const int* __restrict__ dstA, const float* __restrict__ valA,
    int2* __restrict__ DrmZ, int2* __restrict__ DrmA,
    int2* __restrict__ binsCZ, int2* __restrict__ binsCA,
    int E, int nbin, int chunk) {
  __shared__ int2 stage[STHALF];
  __shared__ int cur[NBINMAX];
  __shared__ int ps[256];
  const int t = threadIdx.x;
  int k = blockIdx.x;
  const int* srcp; const int* dstp; const float* valp; int2* Drm; int2* binsC;
  if (k < NBLKC) {
    srcp = srcZ; dstp = dstZ; valp = valZ; Drm = DrmZ; binsC = binsCZ;
  } else {
    k -= NBLKC;
    srcp = srcA; dstp = dstA; valp = valA; Drm = DrmA; binsC = binsCA;
  }
  for (int i = t; i < nbin; i += 256) cur[i] = 0;
  __syncthreads();
  const int e0 = k * chunk, e1 = min(E, e0 + chunk);
  // pass 1: count + capture rank. pk = (bin<<19) | ((d&63)<<13) | rank
  int pk[CEDGE];
#pragma unroll
  for (int j = 0; j < CEDGE; ++j) {
    int e = e0 + t + j * 256;
    if (e < e1) {
      int d = dstp[e];
      int bin = d >> 6;
      int r = atomicAdd(&cur[bin], 1);
      pk[j] = (bin << 19) | ((d & 63) << 13) | r;
    }
  }
  __syncthreads();
  int loc[SEGC], cnt[SEGC];
  int s = 0;
#pragma unroll
  for (int j = 0; j < SEGC; ++j) {
    int i = t * SEGC + j;
    int v = (i < nbin) ? cur[i] : 0;
    loc[j] = s; cnt[j] = v;
    s += v;
  }
  ps[t] = s;
  __syncthreads();
  for (int o = 1; o < 256; o <<= 1) {
    int x = (t >= o) ? ps[t - o] : 0;
    __syncthreads();
    ps[t] += x;
    __syncthreads();
  }
  int ex = ps[t] - s;
#pragma unroll
  for (int j = 0; j < SEGC; ++j) {
    int i = t * SEGC + j;
    if (i < nbin) {
      int o = ex + loc[j];
      Drm[(size_t)k * nbin + i] = make_int2(e0 + o, cnt[j]);
      cur[i] = o;
    }
  }
  __syncthreads();
  const int nE = e1 - e0;
  const int hl = (nE + 1) >> 1;  // <= STHALF
  // placement pass A: target position < hl
#pragma unroll
  for (int j = 0; j < CEDGE; ++j) {
    int e = e0 + t + j * 256;
    if (e < e1) {
      int v = pk[j];
      int p = cur[(unsigned)v >> 19] + (v & 0x1FFF);
      if (p < hl)
        stage[p] = make_int2(srcp[e] | (((v >> 13) & 63) << 17), __float_as_int(valp[e]));
    }
  }
  __syncthreads();
  for (int i = t; i < hl; i += 256) binsC[e0 + i] = stage[i];
  __syncthreads();
  // placement pass B: target position >= hl
#pragma unroll
  for (int j = 0; j < CEDGE; ++j) {
    int e = e0 + t + j * 256;
    if (e < e1) {
      int v = pk[j];
      int p = cur[(unsigned)v >> 19] + (v & 0x1FFF);
      if (p >= hl)
        stage[p - hl] = make_int2(srcp[e] | (((v >> 13) & 63) << 17), __float_as_int(valp[e]));
    }
  }
  __syncthreads();
  for (int i = t; i < nE - hl; i += 256) binsC[e0 + hl + i] = stage[i];
}

// ============================ stage 2 (merged Z+A): bin -> full dst-row sort ============================
// bins2 layout: bin b occupies [b*RSMAX, b*RSMAX+cnt). rowdesc[row] = (start, deg).
// r9: bijective XCD swizzle (m204) so consecutive bins run on the SAME XCD --
// the strided Drm read (64B line = 8 bins) and adjacent per-chunk binsC
// segments then hit in that XCD's L2 instead of being re-fetched 8x.
__global__ __launch_bounds__(256) void row_sort2(
    const int2* __restrict__ DrmZ, const int2* __restrict__ DrmA,
    const int2* __restrict__ binsCZ, const int2* __restrict__ binsCA,
    int2* __restrict__ bins2Z, int2* __restrict__ bins2A,
    int2* __restrict__ rdZ, int2* __restrict__ rdA, int n, int nbin) {
  __shared__ int2 stage[RSMAX];
  __shared__ short rankArr[RSMAX];
  __shared__ int ps[256];
  __shared__ int rcnt[BINROWS];
  __shared__ int roff[BINROWS];
  // bijective XCD swizzle (nwg = 2*nbin, not multiple of 8 -> m204 formula)
  const int nwg = 2 * nbin;
  const int q = nwg >> 3, r = nwg & 7;
  const int xcd = blockIdx.x & 7, idx = blockIdx.x >> 3;
  int b = (xcd < r ? xcd * (q + 1) : r * (q + 1) + (xcd - r) * q) + idx;
  const int t = threadIdx.x;
  const int2* Drm; const int2* binsC; int2* bins2; int2* rowdesc;
  if (b < nbin) {
    Drm = DrmZ; binsC = binsCZ; bins2 = bins2Z; rowdesc = rdZ;
  } else {
    b -= nbin;
    Drm = DrmA; binsC = binsCA; bins2 = bins2A; rowdesc = rdA;
  }
  if (t < BINROWS) rcnt[t] = 0;
  int2 run = Drm[(size_t)t * nbin + b];  // strided read (chunk-major)
  ps[t] = run.y;
  __syncthreads();
  for (int o = 1; o < 256; o <<= 1) {
    int x = (t >= o) ? ps[t - o] : 0;
    __syncthreads();
    ps[t] += x;
    __syncthreads();
  }
  int mystart = ps[t] - run.y;
  for (int j = 0; j < run.y; ++j) {
    int2 en = binsC[run.x + j];
    int idx2 = mystart + j;
    int rr = atomicAdd(&rcnt[(en.x >> 17) & 63], 1);
    if (idx2 < RSMAX) {
      stage[idx2] = en;
      rankArr[idx2] = (short)rr;
    }
  }
  __syncthreads();
  const int bs = b * RSMAX;
  if (t < BINROWS) {  // wave 0 only: scan 64 row counts
    int c = rcnt[t];
    int s = c;
#pragma unroll
    for (int o = 1; o < 64; o <<= 1) {
      int v = __shfl_up(s, o);
      if (t >= o) s += v;
    }
    int excl = s - c;
    int row = b * BINROWS + t;
    if (row < n) rowdesc[row] = make_int2(bs + excl, c);
    roff[t] = excl;
  }
  __syncthreads();
  int total = min(ps[255], RSMAX);
  for (int i = t; i < total; i += 256) {
    int2 en = stage[i];
    int row = (en.x >> 17) & 63;
    bins2[bs + roff[row] + rankArr[i]] = en;  // atomic-free scatter
  }
}

// ============================ SPMM (128 feats), row-sorted, no LDS ============================
// [SACRED inner body: round-0 form. Rewrites r1/r2 and wave-serialization r6
//  all regressed -- 100K independent waves is the design. Do not touch.]
template <bool SCALE>
__global__ __launch_bounds__(128) void spmm128_sorted(
    const int2* __restrict__ rowdesc, const int2* __restrict__ bins2,
    const unsigned short* __restrict__ X, const float* __restrict__ AM,
    unsigned short* __restrict__ Y, int n) {
  int row = (blockIdx.x * 128 + threadIdx.x) >> 6;
  int lane = threadIdx.x & 63;
  if (row >= n) return;
  int2 rd = rowdesc[row];
  int s = rd.x, d = rd.y;
  int half = lane >> 5, l32 = lane & 31;
  float s0 = 0.f, s1 = 0.f, s2 = 0.f, s3 = 0.f;
  for (int kb = 0; kb < d; kb += 64) {
    int rem = min(64, d - kb);
    int2 my = (lane < rem) ? bins2[s + kb + lane] : make_int2(0, 0);  // w==0 pads
    int myc = my.x & 0x1FFFF;
    float myw = __int_as_float(my.y);
    for (int k = 0; k < rem; k += 8) {
#pragma unroll
      for (int st = 0; st < 4; ++st) {
        int idx = k + 2 * st + half;  // <= 63; pad entries have w==0
        int c = __shfl(myc, idx);
        float wv = __shfl(myw, idx);
        uint2 pv = *(const uint2*)(X + (size_t)c * NFEAT + l32 * 4);
        s0 += wv * bf2f(pv.x);
        s1 += wv * bf2f(pv.x >> 16);
        s2 += wv * bf2f(pv.y);
        s3 += wv * bf2f(pv.y >> 16);
      }
    }
  }
  s0 += __shfl_xor(s0, 32); s1 += __shfl_xor(s1, 32);
  s2 += __shfl_xor(s2, 32); s3 += __shfl_xor(s3, 32);
  if (SCALE) {
    float am = AM[row];
    s0 *= am; s1 *= am; s2 *= am; s3 *= am;
  }
  unsigned int pk = half ? (f2bf(s2) | (f2bf(s3) << 16)) : (f2bf(s0) | (f2bf(s1) << 16));
  ((unsigned int*)Y)[(size_t)row * (NFEAT / 2) + l32 * 2 + half] = pk;
}

// ============================ MFMA GEMM 128x128 (+BN+ReLU), flat IO ============================
template <bool FUSE_G2>
__global__ __launch_bounds__(256) void gemm_mfma128(
    const unsigned short* __restrict__ Y, const unsigned short* __restrict__ Wb,
    const float* __restrict__ scale, const float* __restrict__ shift,
    unsigned short* __restrict__ Out,
    const unsigned short* __restrict__ Whi, const unsigned short* __restrict__ Wlo,
    unsigned short* __restrict__ G2, int M) {
  const int wave = threadIdx.x >> 6;
  const int lane = threadIdx.x & 63;
  const int quad = lane >> 4;
  const int l16 = lane & 15;
  const int arow = blockIdx.x * 64 + wave * 16 + l16;
  const bool rv = arow < M;

  f32x4 acc[8];
#pragma unroll
  for (int c = 0; c < 8; ++c) acc[c] = (f32x4){0.f, 0.f, 0.f, 0.f};

#pragma unroll
  for (int kc = 0; kc < 128; kc += 32) {
    bf16x8 a = rv ? *(const bf16x8*)(Y + (size_t)arow * 128 + kc + quad * 8)
                  : (bf16x8){0, 0, 0, 0, 0, 0, 0, 0};
#pragma unroll
    for (int c = 0; c < 8; ++c) {
      bf16x8 b = *(const bf16x8*)(Wb + (size_t)(c * 16 + l16) * 128 + kc + quad * 8);
      acc[c] = __builtin_amdgcn_mfma_f32_16x16x32_bf16(a, b, acc[c], 0, 0, 0);
    }
  }

  const int orow0 = blockIdx.x * 64 + wave * 16 + quad * 4;

  if constexpr (!FUSE_G2) {
#pragma unroll
    for (int c = 0; c < 8; ++c) {
      int col = c * 16 + l16;
      float sc = scale[col], sh = shift[col];
#pragma unroll
      for (int r = 0; r < 4; ++r) {
        int orow = orow0 + r;
        if (orow < M) {
          float v = fmaxf(acc[c][r] * sc + sh, 0.f);
          Out[(size_t)orow * 128 + col] = (unsigned short)f2bf(v);
        }
      }
    }
  } else {
    __shared__ unsigned short Ht[64][136];
    const int lrow0 = wave * 16 + quad * 4;
#pragma unroll
    for (int c = 0; c < 8; ++c) {
      int col = c * 16 + l16;
      float sc = scale[col], sh = shift[col];
#pragma unroll
      for (int r = 0; r < 4; ++r) {
        float v = fmaxf(acc[c][r] * sc + sh, 0.f);
        Ht[lrow0 + r][col] = (unsigned short)f2bf(v);
      }
    }
    __syncthreads();
    bf16x8 af[4];
#pragma unroll
    for (int kc = 0; kc < 4; ++kc)
      af[kc] = *(const bf16x8*)(&Ht[wave * 16 + l16][kc * 32 + quad * 8]);
    f32x4 acc2[4];
#pragma unroll
    for (int c2 = 0; c2 < 4; ++c2) acc2[c2] = (f32x4){0.f, 0.f, 0.f, 0.f};
#pragma unroll
    for (int kc = 0; kc < 4; ++kc) {
#pragma unroll
      for (int c2 = 0; c2 < 4; ++c2) {
        bf16x8 bh = *(const bf16x8*)(Whi + (size_t)(c2 * 16 + l16) * 128 + kc * 32 + quad * 8);
        bf16x8 bl = *(const bf16x8*)(Wlo + (size_t)(c2 * 16 + l16) * 128 + kc * 32 + quad * 8);
        acc2[c2] = __builtin_amdgcn_mfma_f32_16x16x32_bf16(af[kc], bh, acc2[c2], 0, 0, 0);
        acc2[c2] = __builtin_amdgcn_mfma_f32_16x16x32_bf16(af[kc], bl, acc2[c2], 0, 0, 0);
      }
    }
#pragma unroll
    for (int c2 = 0; c2 < 4; ++c2) {
      int col = c2 * 16 + l16;
#pragma unroll
      for (int r = 0; r < 4; ++r) {
        int orow = orow0 + r;
        if (orow < M) G2[(size_t)orow * NCLSP + col] = (unsigned short)f2bf(acc2[c2][r]);
      }
    }
  }
}

// ============================ final: spmm(40) + bias + log_softmax ============================
__global__ __launch_bounds__(128) void spmm_softmax64(
    const int2* __restrict__ rowdesc, const int2* __restrict__ bins2,
    const unsigned short* __restrict__ G2, const float* __restrict__ b2,
    float* __restrict__ out, int n) {
  int row = (blockIdx.x * 128 + threadIdx.x) >> 6;
  int lane = threadIdx.x & 63;
  if (row >= n) return;
  const int eidx = lane >> 4, q = lane & 15;
  const bool vq = q < (NCLS / 4);  // 10 quartets cover the 40 real classes
  float4 bv = vq ? *(const float4*)(b2 + q * 4) : make_float4(0.f, 0.f, 0.f, 0.f);

  int2 rdv = rowdesc[row];
  int s0i = rdv.x, d = rdv.y;
  float a0 = 0.f, a1 = 0.f, a2 = 0.f, a3 = 0.f;
  for (int kb = 0; kb < d; kb += 64) {
    int rem = min(64, d - kb);
    int2 my = (lane < rem) ? bins2[s0i + kb + lane] : make_int2(0, 0);
    int myc = my.x & 0x1FFFF;
    float myw = __int_as_float(my.y);
    int steps = (rem + 3) >> 2;
#pragma unroll 4
    for (int st = 0; st < steps; ++st) {
      int idx = st * 4 + eidx;  // <= 63; pad entries have w==0
      int c = __shfl(myc, idx);
      float wv = __shfl(myw, idx);
      uint2 pv = *(const uint2*)(G2 + (size_t)c * NCLSP + q * 4);
      a0 += wv * bf2f(pv.x);
      a1 += wv * bf2f(pv.x >> 16);
      a2 += wv * bf2f(pv.y);
      a3 += wv * bf2f(pv.y >> 16);
    }
  }
  a0 += __shfl_xor(a0, 16); a1 += __shfl_xor(a1, 16);
  a2 += __shfl_xor(a2, 16); a3 += __shfl_xor(a3, 16);
  a0 += __shfl_xor(a0, 32); a1 += __shfl_xor(a1, 32);
  a2 += __shfl_xor(a2, 32); a3 += __shfl_xor(a3, 32);
  float z0 = a0 + bv.x, z1 = a1 + bv.y, z2 = a2 + bv.z, z3 = a3 + bv.w;
  bool par = (eidx == 0) && vq;
  float m = par ? fmaxf(fmaxf(z0, z1), fmaxf(z2, z3)) : -INFINITY;
#pragma unroll
  for (int o = 1; o < 64; o <<= 1) m = fmaxf(m, __shfl_xor(m, o));
  float ex = par ? (__expf(z0 - m) + __expf(z1 - m) + __expf(z2 - m) + __expf(z3 - m)) : 0.f;
#pragma unroll
  for (int o = 1; o < 64; o <<= 1) ex += __shfl_xor(ex, o);
  float lg = m + __logf(ex);
  if (par) {
    *(float4*)&out[(size_t)row * NCLS + q * 4] =
        make_float4(z0 - lg, z1 - lg, z2 - lg, z3 - lg);
  }
}

// ============================ launch ============================

extern "C" void kernel_launch(void* const* d_in, const int* in_sizes, int n_in,
                              void* d_out, int out_size, void* d_ws, size_t ws_size,
                              hipStream_t stream) {
  const float* x    = (const float*)d_in[0];
  const float* Mv   = (const float*)d_in[1];
  const float* AM   = (const float*)d_in[2];
  const int* srcZ   = (const int*)d_in[3];
  const int* dstZ   = (const int*)d_in[4];
  const float* valsZ= (const float*)d_in[5];
  const int* src    = (const int*)d_in[6];
  const int* dst    = (const int*)d_in[7];
  const float* vals = (const float*)d_in[8];
  const float* W0   = (const float*)d_in[9];
  const float* b0   = (const float*)d_in[10];
  const float* g0   = (const float*)d_in[11];
  const float* be0  = (const float*)d_in[12];
  const float* rm0  = (const float*)d_in[13];
  const float* rv0  = (const float*)d_in[14];
  const float* W1   = (const float*)d_in[15];
  const float* b1   = (const float*)d_in[16];
  const float* g1   = (const float*)d_in[17];
  const float* be1  = (const float*)d_in[18];
  const float* rm1  = (const float*)d_in[19];
  const float* rv1  = (const float*)d_in[20];
  const float* W2   = (const float*)d_in[21];
  const float* b2   = (const float*)d_in[22];
  float* out = (float*)d_out;

  const int N = in_sizes[1];  // M has shape (N,1)
  const int E = in_sizes[3];
  const int NBIN = (N + BINROWS - 1) / BINROWS;
  const int CHUNK = (E + NBLKC - 1) / NBLKC;  // 6250 <= CHUNKMAX

  char* w = (char*)d_ws;
  size_t off = 0;
  auto alloc = [&](size_t bytes) -> void* {
    void* p = w + off;
    off = (off + bytes + 255) & ~(size_t)255;
    return p;
  };
  const size_t bins2Bytes = (size_t)NBIN * RSMAX * 8;     // 25.6MB fixed-stride layout
  const size_t bufBytes = (size_t)N * NFEAT * 2;          // 25.6MB
  int2* binsCZ = (int2*)alloc((size_t)NBLKC * CHUNK * 8); // 12.8MB chunk-ordered stage (Z)
  int2* binsCA = (int2*)alloc((size_t)NBLKC * CHUNK * 8); // 12.8MB chunk-ordered stage (A)
  int2* bins2A = (int2*)alloc(bins2Bytes);                // lives to the end
  int2* rdZ = (int2*)alloc((size_t)N * 8);                // rowdesc (start,deg) Z
  int2* rdA = (int2*)alloc((size_t)N * 8);                // rowdesc (start,deg) A
  unsigned short* xm = (unsigned short*)alloc(bufBytes);  // 25.6MB
  unsigned short* bufA = (unsigned short*)alloc(bufBytes);                 // Drm -> Y0 -> Y1
  unsigned short* bufB = (unsigned short*)alloc(bins2Bytes > bufBytes ? bins2Bytes : bufBytes);
  float* sc0 = (float*)alloc(128 * 4);
  float* sh0 = (float*)alloc(128 * 4);
  float* sc1 = (float*)alloc(128 * 4);
  float* sh1 = (float*)alloc(128 * 4);
  unsigned short* Wb0 = (unsigned short*)alloc(128 * 128 * 2);
  unsigned short* Wb1 = (unsigned short*)alloc(128 * 128 * 2);
  unsigned short* W2hi = (unsigned short*)alloc(64 * 128 * 2);
  unsigned short* W2lo = (unsigned short*)alloc(64 * 128 * 2);
  // aliases:
  //  - DrmZ/DrmA (3.2MB each) live in bufA until row_sort2 done; spmmZ then
  //    writes Y0 into bufA.
  //  - bins2Z (25.6MB fixed-stride) lives in bufB until spmmZ consumes it
  //    (gemm0 then overwrites bufB with H0); G2 (N x 64 bf16 = 12.8MB) lives in
  //    bufB after H0 dies (fused gemm1 reads Y1 from bufA, writes G2 to bufB).
  const size_t drmBytes = (size_t)NBLKC * NBIN * 8;  // 3,201,024 (mult of 256)
  int2* DrmZ = (int2*)((char*)bufA + 0 * drmBytes);
  int2* DrmA = (int2*)((char*)bufA + 1 * drmBytes);
  int2* bins2Z = (int2*)bufB;
  unsigned short* G2 = bufB;

  const int RB2 = (N + 1) / 2;  // 2 rows (waves) per 128-thread block
  const int GB64 = (N + 63) / 64;
  const int CONVB = (N * (NFEAT / 8) + 255) / 256;

  prep_all<<<21 + CONVB, 256, 0, stream>>>(b0, g0, be0, rm0, rv0, b1, g1, be1, rm1, rv1,
                                           sc0, sh0, sc1, sh1, W0, W1, W2,
                                           Wb0, Wb1, W2hi, W2lo, x, Mv, xm, N);

  // --- both adjacencies: chunk-bin sort -> full row sort (merged launches) ---
  bin_sort2<<<2 * NBLKC, 256, 0, stream>>>(srcZ, dstZ, valsZ, src, dst, vals,
                                           DrmZ, DrmA, binsCZ, binsCA, E, NBIN, CHUNK);
  row_sort2<<<2 * NBIN, 256, 0, stream>>>(DrmZ, DrmA, binsCZ, binsCA,
                                          bins2Z, bins2A, rdZ, rdA, N, NBIN);

  // layer 0: Y0 = spmm(adjZ, M*x)*AM ; H0 = relu(bn(Y0 @ W0^T + b0))
  spmm128_sorted<true><<<RB2, 128, 0, stream>>>(rdZ, bins2Z, xm, AM, bufA, N);
  gemm_mfma128<false><<<GB64, 256, 0, stream>>>(bufA, Wb0, sc0, sh0, bufB,
                                                nullptr, nullptr, nullptr, N);

  // layer 1+2: Y1 = spmm(adj, H0) ; fused: H1 = relu(bn(Y1 @ W1^T + b1)) on-chip,
  // G2 = bf16(H1 @ W2^T) padded to 64 cols written directly.
  spmm128_sorted<false><<<RB2, 128, 0, stream>>>(rdA, bins2A, bufB,
                                                 (const float*)nullptr, bufA, N);
  gemm_mfma128<true><<<GB64, 256, 0, stream>>>(bufA, Wb1, sc1, sh1, nullptr,
                                               W2hi, W2lo, G2, N);

  // out = log_softmax(spmm(adj, G2) + b2)
  spmm_softmax64<<<RB2, 128, 0, stream>>>(rdA, bins2A, G2, b2, out, N);
}

// Round 10
// 492.772 us; speedup vs baseline: 1.0818x; 1.0030x over previous
//
#include <hip/hip_runtime.h>
#include <math.h>

#define NFEAT 128
#define NCLS 40       // real class count; G2 row stride (shorts) = 40 (80B)
#define BINROWS 64    // rows per bin
#define NBINMAX 1600  // >= ceil(100000/64)=1563
#define NBLKC 256     // chunks for the binning sort
#define CHUNKMAX 6400 // >= ceil(1600000/256)=6250
#define STHALF 3200   // half-chunk LDS stage (>= ceil(6250/2)=3125); 25.6KB
#define CEDGE 25      // CHUNKMAX/256: max edges per thread per chunk
#define SEGC 7        // ceil(NBINMAX/256)
#define RSMAX 2048    // per-bin capacity in bins2 (fixed stride) + row_sort LDS stage

typedef short bf16x8 __attribute__((ext_vector_type(8)));
typedef float f32x4 __attribute__((ext_vector_type(4)));

// ---------- bf16 helpers ----------
__device__ __forceinline__ float bf2f(unsigned int lo16) {
  return __uint_as_float((lo16 & 0xffffu) << 16);
}
__device__ __forceinline__ unsigned int f2bf(float x) {  // round-to-nearest-even
  unsigned int u = __float_as_uint(x);
  return (u + 0x7fffu + ((u >> 16) & 1u)) >> 16;
}

// Wave-level inclusive scan (64 lanes) -- replaces 16-barrier LDS scans.
__device__ __forceinline__ int wave_incl_scan(int v, int lane64) {
  int s = v;
#pragma unroll
  for (int o = 1; o < 64; o <<= 1) {
    int x = __shfl_up(s, o);
    if (lane64 >= o) s += x;
  }
  return s;
}

// ============================ merged prep: BN fold + W conv + x*M conv ============================
__global__ __launch_bounds__(256) void prep_all(
    const float* b0, const float* g0, const float* be0,
    const float* rm0, const float* rv0,
    const float* b1, const float* g1, const float* be1,
    const float* rm1, const float* rv1,
    float* sc0, float* sh0, float* sc1, float* sh1,
    const float* __restrict__ W0, const float* __restrict__ W1,
    const float* __restrict__ W2,
    unsigned short* __restrict__ Wb0, unsigned short* __restrict__ Wb1,
    unsigned short* __restrict__ W2hi, unsigned short* __restrict__ W2lo,
    const float* __restrict__ x, const float* __restrict__ Mv,
    unsigned short* __restrict__ xm, int n) {
  int t = threadIdx.x;
  if (blockIdx.x == 0) {
    if (t < 128) {
      float s = g0[t] * rsqrtf(rv0[t] + 1e-5f);
      sc0[t] = s;
      sh0[t] = (b0[t] - rm0[t]) * s + be0[t];
    } else {
      int i = t - 128;
      float s = g1[i] * rsqrtf(rv1[i] + 1e-5f);
      sc1[i] = s;
      sh1[i] = (b1[i] - rm1[i]) * s + be1[i];
    }
    return;
  }
  if (blockIdx.x <= 20) {
    int i = (blockIdx.x - 1) * 256 + t;  // 5120 threads, 8 elems each
    if (i < 4096) {
      const float* W = (i < 2048) ? W0 : W1;
      unsigned short* Wb = (i < 2048) ? Wb0 : Wb1;
      int j = (i < 2048) ? i : i - 2048;
      const float4* p = (const float4*)(W + (size_t)j * 8);
      float4 v0 = p[0], v1 = p[1];
      unsigned int o0 = f2bf(v0.x) | (f2bf(v0.y) << 16);
      unsigned int o1 = f2bf(v0.z) | (f2bf(v0.w) << 16);
      unsigned int o2 = f2bf(v1.x) | (f2bf(v1.y) << 16);
      unsigned int o3 = f2bf(v1.z) | (f2bf(v1.w) << 16);
      ((uint4*)Wb)[j] = make_uint4(o0, o1, o2, o3);
    } else {
      int j = i - 4096;  // chunk of 8 within padded 64x128
      int r = j >> 4;    // padded out-row
      float v[8] = {0.f, 0.f, 0.f, 0.f, 0.f, 0.f, 0.f, 0.f};
      if (r < NCLS) {  // j*8 == r*128 + (j&15)*8 exactly
        const float4* p = (const float4*)(W2 + (size_t)j * 8);
        float4 a = p[0], b = p[1];
        v[0] = a.x; v[1] = a.y; v[2] = a.z; v[3] = a.w;
        v[4] = b.x; v[5] = b.y; v[6] = b.z; v[7] = b.w;
      }
      unsigned int h[8], l[8];
#pragma unroll
      for (int q = 0; q < 8; ++q) {
        h[q] = f2bf(v[q]);
        l[q] = f2bf(v[q] - bf2f(h[q]));
      }
      ((uint4*)W2hi)[j] = make_uint4(h[0] | (h[1] << 16), h[2] | (h[3] << 16),
                                     h[4] | (h[5] << 16), h[6] | (h[7] << 16));
      ((uint4*)W2lo)[j] = make_uint4(l[0] | (l[1] << 16), l[2] | (l[3] << 16),
                                     l[4] | (l[5] << 16), l[6] | (l[7] << 16));
    }
    return;
  }
  int i = (blockIdx.x - 21) * 256 + t;  // one 8-elem chunk per thread
  if (i >= n * (NFEAT / 8)) return;
  int row = i >> 4;
  float m = Mv[row];
  const float4* p = (const float4*)(x + (size_t)i * 8);
  float4 v0 = p[0], v1 = p[1];
  unsigned int o0 = f2bf(v0.x * m) | (f2bf(v0.y * m) << 16);
  unsigned int o1 = f2bf(v0.z * m) | (f2bf(v0.w * m) << 16);
  unsigned int o2 = f2bf(v1.x * m) | (f2bf(v1.y * m) << 16);
  unsigned int o3 = f2bf(v1.z * m) | (f2bf(v1.w * m) << 16);
  ((uint4*)xm)[i] = make_uint4(o0, o1, o2, o3);
}

// ============================ stage 1 (merged Z+A): chunk -> 64-row bins ============================
// LDS staging is LOAD-BEARING (round-3 lesson: removing it -> 6x write
// amplification). r9: two half-chunk placement passes (25.6KB stage -> 4
// blocks/CU). r10: wave-shfl scan (1 barrier instead of 16).
__global__ __launch_bounds__(256) void bin_sort2(
    const int* __restrict__ srcZ, const int* __restrict__ dstZ, const float* __restrict__ valZ,
    const int* __restrict__ srcA, const int* __restrict__ dstA, const float* __restrict__ valA,
    int2* __restrict__ DrmZ, int2* __restrict__ DrmA,
    int2* __restrict__ binsCZ, int2* __restrict__ binsCA,
    int E, int nbin, int chunk) {
  __shared__ int2 stage[STHALF];
  __shared__ int cur[NBINMAX];
  __shared__ int wsum[4];
  const int t = threadIdx.x;
  int k = blockIdx.x;
  const int* srcp; const int* dstp; const float* valp; int2* Drm; int2* binsC;
  if (k < NBLKC) {
    srcp = srcZ; dstp = dstZ; valp = valZ; Drm = DrmZ; binsC = binsCZ;
  } else {
    k -= NBLKC;
    srcp = srcA; dstp = dstA; valp = valA; Drm = DrmA; binsC = binsCA;
  }
  for (int i = t; i < nbin; i += 256) cur[i] = 0;
  __syncthreads();
  const int e0 = k * chunk, e1 = min(E, e0 + chunk);
  // pass 1: count + capture rank. pk = (bin<<19) | ((d&63)<<13) | rank
  int pk[CEDGE];
#pragma unroll
  for (int j = 0; j < CEDGE; ++j) {
    int e = e0 + t + j * 256;
    if (e < e1) {
      int d = dstp[e];
      int bin = d >> 6;
      int r = atomicAdd(&cur[bin], 1);
      pk[j] = (bin << 19) | ((d & 63) << 13) | r;
    }
  }
  __syncthreads();
  int loc[SEGC], cnt[SEGC];
  int s = 0;
#pragma unroll
  for (int j = 0; j < SEGC; ++j) {
    int i = t * SEGC + j;
    int v = (i < nbin) ? cur[i] : 0;
    loc[j] = s; cnt[j] = v;
    s += v;
  }
  // wave-shfl scan across 256 threads (1 barrier)
  int incl = wave_incl_scan(s, t & 63);
  if ((t & 63) == 63) wsum[t >> 6] = incl;
  __syncthreads();  // wsum ready; all cur reads above done
  int base = 0;
#pragma unroll
  for (int wv = 0; wv < 4; ++wv)
    if (wv < (t >> 6)) base += wsum[wv];
  int ex = base + incl - s;
#pragma unroll
  for (int j = 0; j < SEGC; ++j) {
    int i = t * SEGC + j;
    if (i < nbin) {
      int o = ex + loc[j];
      Drm[(size_t)k * nbin + i] = make_int2(e0 + o, cnt[j]);
      cur[i] = o;
    }
  }
  __syncthreads();
  const int nE = e1 - e0;
  const int hl = (nE + 1) >> 1;  // <= STHALF
  // placement pass A: target position < hl
#pragma unroll
  for (int j = 0; j < CEDGE; ++j) {
    int e = e0 + t + j * 256;
    if (e < e1) {
      int v = pk[j];
      int p = cur[(unsigned)v >> 19] + (v & 0x1FFF);
      if (p < hl)
        stage[p] = make_int2(srcp[e] | (((v >> 13) & 63) << 17), __float_as_int(valp[e]));
    }
  }
  __syncthreads();
  for (int i = t; i < hl; i += 256) binsC[e0 + i] = stage[i];
  __syncthreads();
  // placement pass B: target position >= hl
#pragma unroll
  for (int j = 0; j < CEDGE; ++j) {
    int e = e0 + t + j * 256;
    if (e < e1) {
      int v = pk[j];
      int p = cur[(unsigned)v >> 19] + (v & 0x1FFF);
      if (p >= hl)
        stage[p - hl] = make_int2(srcp[e] | (((v >> 13) & 63) << 17), __float_as_int(valp[e]));
    }
  }
  __syncthreads();
  for (int i = t; i < nE - hl; i += 256) binsC[e0 + hl + i] = stage[i];
}

// ============================ stage 2 (merged Z+A): bin -> full dst-row sort ============================
// bins2 layout: bin b occupies [b*RSMAX, b*RSMAX+cnt). rowdesc[row] = (start, deg).
// r9: bijective XCD swizzle (consecutive bins share an XCD's L2 for the strided
// Drm lines + adjacent binsC runs). r10: wave-shfl scan (1 barrier).
__global__ __launch_bounds__(256) void row_sort2(
    const int2* __restrict__ DrmZ, const int2* __restrict__ DrmA,
    const int2* __restrict__ binsCZ, const int2* __restrict__ binsCA,
    int2* __restrict__ bins2Z, int2* __restrict__ bins2A,
    int2* __restrict__ rdZ, int2* __restrict__ rdA, int n, int nbin) {
  __shared__ int2 stage[RSMAX];
  __shared__ short rankArr[RSMAX];
  __shared__ int wsum[4];
  __shared__ int rcnt[BINROWS];
  __shared__ int roff[BINROWS];
  // bijective XCD swizzle (nwg = 2*nbin, not multiple of 8 -> m204 formula)
  const int nwg = 2 * nbin;
  const int q = nwg >> 3, r = nwg & 7;
  const int xcd = blockIdx.x & 7, idx = blockIdx.x >> 3;
  int b = (xcd < r ? xcd * (q + 1) : r * (q + 1) + (xcd - r) * q) + idx;
  const int t = threadIdx.x;
  const int2* Drm; const int2* binsC; int2* bins2; int2* rowdesc;
  if (b < nbin) {
    Drm = DrmZ; binsC = binsCZ; bins2 = bins2Z; rowdesc = rdZ;
  } else {
    b -= nbin;
    Drm = DrmA; binsC = binsCA; bins2 = bins2A; rowdesc = rdA;
  }
  if (t < BINROWS) rcnt[t] = 0;
  int2 run = Drm[(size_t)t * nbin + b];  // strided read (chunk-major)
  int incl = wave_incl_scan(run.y, t & 63);
  if ((t & 63) == 63) wsum[t >> 6] = incl;
  __syncthreads();  // wsum ready + rcnt zeroed
  int base = 0;
#pragma unroll
  for (int wv = 0; wv < 4; ++wv)
    if (wv < (t >> 6)) base += wsum[wv];
  int mystart = base + incl - run.y;
  int totalAll = wsum[0] + wsum[1] + wsum[2] + wsum[3];
  for (int j = 0; j < run.y; ++j) {
    int2 en = binsC[run.x + j];
    int idx2 = mystart + j;
    int rr = atomicAdd(&rcnt[(en.x >> 17) & 63], 1);
    if (idx2 < RSMAX) {
      stage[idx2] = en;
      rankArr[idx2] = (short)rr;
    }
  }
  __syncthreads();
  const int bs = b * RSMAX;
  if (t < BINROWS) {  // wave 0 only: scan 64 row counts
    int c = rcnt[t];
    int s = c;
#pragma unroll
    for (int o = 1; o < 64; o <<= 1) {
      int v = __shfl_up(s, o);
      if (t >= o) s += v;
    }
    int excl = s - c;
    int row = b * BINROWS + t;
    if (row < n) rowdesc[row] = make_int2(bs + excl, c);
    roff[t] = excl;
  }
  __syncthreads();
  int total = min(totalAll, RSMAX);
  for (int i = t; i < total; i += 256) {
    int2 en = stage[i];
    int row = (en.x >> 17) & 63;
    bins2[bs + roff[row] + rankArr[i]] = en;  // atomic-free scatter
  }
}

// ============================ SPMM (128 feats), row-sorted, no LDS ============================
// [SACRED inner body: round-0 form. Rewrites r1/r2 and wave-serialization r6
//  all regressed -- 100K independent waves is the design. Do not touch.]
template <bool SCALE>
__global__ __launch_bounds__(128) void spmm128_sorted(
    const int2* __restrict__ rowdesc, const int2* __restrict__ bins2,
    const unsigned short* __restrict__ X, const float* __restrict__ AM,
    unsigned short* __restrict__ Y, int n) {
  int row = (blockIdx.x * 128 + threadIdx.x) >> 6;
  int lane = threadIdx.x & 63;
  if (row >= n) return;
  int2 rd = rowdesc[row];
  int s = rd.x, d = rd.y;
  int half = lane >> 5, l32 = lane & 31;
  float s0 = 0.f, s1 = 0.f, s2 = 0.f, s3 = 0.f;
  for (int kb = 0; kb < d; kb += 64) {
    int rem = min(64, d - kb);
    int2 my = (lane < rem) ? bins2[s + kb + lane] : make_int2(0, 0);  // w==0 pads
    int myc = my.x & 0x1FFFF;
    float myw = __int_as_float(my.y);
    for (int k = 0; k < rem; k += 8) {
#pragma unroll
      for (int st = 0; st < 4; ++st) {
        int idx = k + 2 * st + half;  // <= 63; pad entries have w==0
        int c = __shfl(myc, idx);
        float wv = __shfl(myw, idx);
        uint2 pv = *(const uint2*)(X + (size_t)c * NFEAT + l32 * 4);
        s0 += wv * bf2f(pv.x);
        s1 += wv * bf2f(pv.x >> 16);
        s2 += wv * bf2f(pv.y);
        s3 += wv * bf2f(pv.y >> 16);
      }
    }
  }
  s0 += __shfl_xor(s0, 32); s1 += __shfl_xor(s1, 32);
  s2 += __shfl_xor(s2, 32); s3 += __shfl_xor(s3, 32);
  if (SCALE) {
    float am = AM[row];
    s0 *= am; s1 *= am; s2 *= am; s3 *= am;
  }
  unsigned int pk = half ? (f2bf(s2) | (f2bf(s3) << 16)) : (f2bf(s0) | (f2bf(s1) << 16));
  ((unsigned int*)Y)[(size_t)row * (NFEAT / 2) + l32 * 2 + half] = pk;
}

// ============================ MFMA GEMM 128x128 (+BN+ReLU), flat IO ============================
// FUSE_G2=false (layer 0): Out = relu(bn(Y@W^T)) as bf16.
// FUSE_G2=true  (layer 1): H1 = relu(bn(Y@W1^T)) stays on-chip (LDS transpose
// staging), then G2[M x 40] (80B rows) = H1 @ W2^T (hi+lo bf16 split). r10:
// c2=3 MFMA block dropped (cols 48-63 were all-zero pad), c2=2 store guarded.
template <bool FUSE_G2>
__global__ __launch_bounds__(256) void gemm_mfma128(
    const unsigned short* __restrict__ Y, const unsigned short* __restrict__ Wb,
    const float* __restrict__ scale, const float* __restrict__ shift,
    unsigned short* __restrict__ Out,
    const unsigned short* __restrict__ Whi, const unsigned short* __restrict__ Wlo,
    unsigned short* __restrict__ G2, int M) {
  const int wave = threadIdx.x >> 6;
  const int lane = threadIdx.x & 63;
  const int quad = lane >> 4;
  const int l16 = lane & 15;
  const int arow = blockIdx.x * 64 + wave * 16 + l16;
  const bool rv = arow < M;

  f32x4 acc[8];
#pragma unroll
  for (int c = 0; c < 8; ++c) acc[c] = (f32x4){0.f, 0.f, 0.f, 0.f};

#pragma unroll
  for (int kc = 0; kc < 128; kc += 32) {
    bf16x8 a = rv ? *(const bf16x8*)(Y + (size_t)arow * 128 + kc + quad * 8)
                  : (bf16x8){0, 0, 0, 0, 0, 0, 0, 0};
#pragma unroll
    for (int c = 0; c < 8; ++c) {
      bf16x8 b = *(const bf16x8*)(Wb + (size_t)(c * 16 + l16) * 128 + kc + quad * 8);
      acc[c] = __builtin_amdgcn_mfma_f32_16x16x32_bf16(a, b, acc[c], 0, 0, 0);
    }
  }

  const int orow0 = blockIdx.x * 64 + wave * 16 + quad * 4;

  if constexpr (!FUSE_G2) {
#pragma unroll
    for (int c = 0; c < 8; ++c) {
      int col = c * 16 + l16;
      float sc = scale[col], sh = shift[col];
#pragma unroll
      for (int r = 0; r < 4; ++r) {
        int orow = orow0 + r;
        if (orow < M) {
          float v = fmaxf(acc[c][r] * sc + sh, 0.f);
          Out[(size_t)orow * 128 + col] = (unsigned short)f2bf(v);
        }
      }
    }
  } else {
    __shared__ unsigned short Ht[64][136];
    const int lrow0 = wave * 16 + quad * 4;
#pragma unroll
    for (int c = 0; c < 8; ++c) {
      int col = c * 16 + l16;
      float sc = scale[col], sh = shift[col];
#pragma unroll
      for (int r = 0; r < 4; ++r) {
        float v = fmaxf(acc[c][r] * sc + sh, 0.f);
        Ht[lrow0 + r][col] = (unsigned short)f2bf(v);
      }
    }
    __syncthreads();
    bf16x8 af[4];
#pragma unroll
    for (int kc = 0; kc < 4; ++kc)
      af[kc] = *(const bf16x8*)(&Ht[wave * 16 + l16][kc * 32 + quad * 8]);
    f32x4 acc2[3];
#pragma unroll
    for (int c2 = 0; c2 < 3; ++c2) acc2[c2] = (f32x4){0.f, 0.f, 0.f, 0.f};
#pragma unroll
    for (int kc = 0; kc < 4; ++kc) {
#pragma unroll
      for (int c2 = 0; c2 < 3; ++c2) {
        bf16x8 bh = *(const bf16x8*)(Whi + (size_t)(c2 * 16 + l16) * 128 + kc * 32 + quad * 8);
        bf16x8 bl = *(const bf16x8*)(Wlo + (size_t)(c2 * 16 + l16) * 128 + kc * 32 + quad * 8);
        acc2[c2] = __builtin_amdgcn_mfma_f32_16x16x32_bf16(af[kc], bh, acc2[c2], 0, 0, 0);
        acc2[c2] = __builtin_amdgcn_mfma_f32_16x16x32_bf16(af[kc], bl, acc2[c2], 0, 0, 0);
      }
    }
#pragma unroll
    for (int c2 = 0; c2 < 3; ++c2) {
      int col = c2 * 16 + l16;
      if (col < NCLS) {
#pragma unroll
        for (int r = 0; r < 4; ++r) {
          int orow = orow0 + r;
          if (orow < M) G2[(size_t)orow * NCLS + col] = (unsigned short)f2bf(acc2[c2][r]);
        }
      }
    }
  }
}

// ============================ final: spmm(40) + bias + log_softmax ============================
// G2 rows are 40 bf16 (80B). Gather by lanes q<10 only (10 x 8B = one row);
// q>=10 lanes idle through the gather (they contributed only zeros before).
__global__ __launch_bounds__(128) void spmm_softmax64(
    const int2* __restrict__ rowdesc, const int2* __restrict__ bins2,
    const unsigned short* __restrict__ G2, const float* __restrict__ b2,
    float* __restrict__ out, int n) {
  int row = (blockIdx.x * 128 + threadIdx.x) >> 6;
  int lane = threadIdx.x & 63;
  if (row >= n) return;
  const int eidx = lane >> 4, q = lane & 15;
  const bool vq = q < (NCLS / 4);  // 10 quartets cover the 40 real classes
  float4 bv = vq ? *(const float4*)(b2 + q * 4) : make_float4(0.f, 0.f, 0.f, 0.f);

  int2 rdv = rowdesc[row];
  int s0i = rdv.x, d = rdv.y;
  float a0 = 0.f, a1 = 0.f, a2 = 0.f, a3 = 0.f;
  for (int kb = 0; kb < d; kb += 64) {
    int rem = min(64, d - kb);
    int2 my = (lane < rem) ? bins2[s0i + kb + lane] : make_int2(0, 0);
    int myc = my.x & 0x1FFFF;
    float myw = __int_as_float(my.y);
    int steps = (rem + 3) >> 2;
#pragma unroll 4
    for (int st = 0; st < steps; ++st) {
      int idx = st * 4 + eidx;  // <= 63; pad entries have w==0
      int c = __shfl(myc, idx);
      float wv = __shfl(myw, idx);
      if (vq) {
        uint2 pv = *(const uint2*)(G2 + (size_t)c * NCLS + q * 4);
        a0 += wv * bf2f(pv.x);
        a1 += wv * bf2f(pv.x >> 16);
        a2 += wv * bf2f(pv.y);
        a3 += wv * bf2f(pv.y >> 16);
      }
    }
  }
  a0 += __shfl_xor(a0, 16); a1 += __shfl_xor(a1, 16);
  a2 += __shfl_xor(a2, 16); a3 += __shfl_xor(a3, 16);
  a0 += __shfl_xor(a0, 32); a1 += __shfl_xor(a1, 32);
  a2 += __shfl_xor(a2, 32); a3 += __shfl_xor(a3, 32);
  float z0 = a0 + bv.x, z1 = a1 + bv.y, z2 = a2 + bv.z, z3 = a3 + bv.w;
  bool par = (eidx == 0) && vq;
  float m = par ? fmaxf(fmaxf(z0, z1), fmaxf(z2, z3)) : -INFINITY;
#pragma unroll
  for (int o = 1; o < 64; o <<= 1) m = fmaxf(m, __shfl_xor(m, o));
  float ex = par ? (__expf(z0 - m) + __expf(z1 - m) + __expf(z2 - m) + __expf(z3 - m)) : 0.f;
#pragma unroll
  for (int o = 1; o < 64; o <<= 1) ex += __shfl_xor(ex, o);
  float lg = m + __logf(ex);
  if (par) {
    *(float4*)&out[(size_t)row * NCLS + q * 4] =
        make_float4(z0 - lg, z1 - lg, z2 - lg, z3 - lg);
  }
}

// ============================ launch ============================

extern "C" void kernel_launch(void* const* d_in, const int* in_sizes, int n_in,
                              void* d_out, int out_size, void* d_ws, size_t ws_size,
                              hipStream_t stream) {
  const float* x    = (const float*)d_in[0];
  const float* Mv   = (const float*)d_in[1];
  const float* AM   = (const float*)d_in[2];
  const int* srcZ   = (const int*)d_in[3];
  const int* dstZ   = (const int*)d_in[4];
  const float* valsZ= (const float*)d_in[5];
  const int* src    = (const int*)d_in[6];
  const int* dst    = (const int*)d_in[7];
  const float* vals = (const float*)d_in[8];
  const float* W0   = (const float*)d_in[9];
  const float* b0   = (const float*)d_in[10];
  const float* g0   = (const float*)d_in[11];
  const float* be0  = (const float*)d_in[12];
  const float* rm0  = (const float*)d_in[13];
  const float* rv0  = (const float*)d_in[14];
  const float* W1   = (const float*)d_in[15];
  const float* b1   = (const float*)d_in[16];
  const float* g1   = (const float*)d_in[17];
  const float* be1  = (const float*)d_in[18];
  const float* rm1  = (const float*)d_in[19];
  const float* rv1  = (const float*)d_in[20];
  const float* W2   = (const float*)d_in[21];
  const float* b2   = (const float*)d_in[22];
  float* out = (float*)d_out;

  const int N = in_sizes[1];  // M has shape (N,1)
  const int E = in_sizes[3];
  const int NBIN = (N + BINROWS - 1) / BINROWS;
  const int CHUNK = (E + NBLKC - 1) / NBLKC;  // 6250 <= CHUNKMAX

  char* w = (char*)d_ws;
  size_t off = 0;
  auto alloc = [&](size_t bytes) -> void* {
    void* p = w + off;
    off = (off + bytes + 255) & ~(size_t)255;
    return p;
  };
  const size_t bins2Bytes = (size_t)NBIN * RSMAX * 8;     // 25.6MB fixed-stride layout
  const size_t bufBytes = (size_t)N * NFEAT * 2;          // 25.6MB
  int2* binsCZ = (int2*)alloc((size_t)NBLKC * CHUNK * 8); // 12.8MB chunk-ordered stage (Z)
  int2* binsCA = (int2*)alloc((size_t)NBLKC * CHUNK * 8); // 12.8MB chunk-ordered stage (A)
  int2* bins2A = (int2*)alloc(bins2Bytes);                // lives to the end
  int2* rdZ = (int2*)alloc((size_t)N * 8);                // rowdesc (start,deg) Z
  int2* rdA = (int2*)alloc((size_t)N * 8);                // rowdesc (start,deg) A
  unsigned short* xm = (unsigned short*)alloc(bufBytes);  // 25.6MB
  unsigned short* bufA = (unsigned short*)alloc(bufBytes);                 // Drm -> Y0 -> Y1
  unsigned short* bufB = (unsigned short*)alloc(bins2Bytes > bufBytes ? bins2Bytes : bufBytes);
  float* sc0 = (float*)alloc(128 * 4);
  float* sh0 = (float*)alloc(128 * 4);
  float* sc1 = (float*)alloc(128 * 4);
  float* sh1 = (float*)alloc(128 * 4);
  unsigned short* Wb0 = (unsigned short*)alloc(128 * 128 * 2);
  unsigned short* Wb1 = (unsigned short*)alloc(128 * 128 * 2);
  unsigned short* W2hi = (unsigned short*)alloc(64 * 128 * 2);
  unsigned short* W2lo = (unsigned short*)alloc(64 * 128 * 2);
  // aliases:
  //  - DrmZ/DrmA (3.2MB each) live in bufA until row_sort2 done; spmmZ then
  //    writes Y0 into bufA.
  //  - bins2Z (25.6MB fixed-stride) lives in bufB until spmmZ consumes it
  //    (gemm0 then overwrites bufB with H0); G2 (N x 40 bf16 = 8MB) lives in
  //    bufB after H0 dies (fused gemm1 reads Y1 from bufA, writes G2 to bufB).
  const size_t drmBytes = (size_t)NBLKC * NBIN * 8;  // 3,201,024 (mult of 256)
  int2* DrmZ = (int2*)((char*)bufA + 0 * drmBytes);
  int2* DrmA = (int2*)((char*)bufA + 1 * drmBytes);
  int2* bins2Z = (int2*)bufB;
  unsigned short* G2 = bufB;

  const int RB2 = (N + 1) / 2;  // 2 rows (waves) per 128-thread block
  const int GB64 = (N + 63) / 64;
  const int CONVB = (N * (NFEAT / 8) + 255) / 256;

  prep_all<<<21 + CONVB, 256, 0, stream>>>(b0, g0, be0, rm0, rv0, b1, g1, be1, rm1, rv1,
                                           sc0, sh0, sc1, sh1, W0, W1, W2,
                                           Wb0, Wb1, W2hi, W2lo, x, Mv, xm, N);

  // --- both adjacencies: chunk-bin sort -> full row sort (merged launches) ---
  bin_sort2<<<2 * NBLKC, 256, 0, stream>>>(srcZ, dstZ, valsZ, src, dst, vals,
                                           DrmZ, DrmA, binsCZ, binsCA, E, NBIN, CHUNK);
  row_sort2<<<2 * NBIN, 256, 0, stream>>>(DrmZ, DrmA, binsCZ, binsCA,
                                          bins2Z, bins2A, rdZ, rdA, N, NBIN);

  // layer 0: Y0 = spmm(adjZ, M*x)*AM ; H0 = relu(bn(Y0 @ W0^T + b0))
  spmm128_sorted<true><<<RB2, 128, 0, stream>>>(rdZ, bins2Z, xm, AM, bufA, N);
  gemm_mfma128<false><<<GB64, 256, 0, stream>>>(bufA, Wb0, sc0, sh0, bufB,
                                                nullptr, nullptr, nullptr, N);

  // layer 1+2: Y1 = spmm(adj, H0) ; fused: H1 = relu(bn(Y1 @ W1^T + b1)) on-chip,
  // G2 = bf16(H1 @ W2^T) (40 cols, 80B rows) written directly.
  spmm128_sorted<false><<<RB2, 128, 0, stream>>>(rdA, bins2A, bufB,
                                                 (const float*)nullptr, bufA, N);
  gemm_mfma128<true><<<GB64, 256, 0, stream>>>(bufA, Wb1, sc1, sh1, nullptr,
                                               W2hi, W2lo, G2, N);

  // out = log_softmax(spmm(adj, G2) + b2)
  spmm_softmax64<<<RB2, 128, 0, stream>>>(rdA, bins2A, G2, b2, out, N);
}

// Round 11
// 480.906 us; speedup vs baseline: 1.1085x; 1.0247x over previous
//
#include <hip/hip_runtime.h>
#include <math.h>

#define NFEAT 128
#define NCLS 40       // real class count; G2 row stride (shorts) = 40 (80B)
#define BINROWS 64    // rows per bin
#define NBINMAX 1600  // >= ceil(100000/64)=1563
#define NBLKC 256     // chunks for the binning sort
#define CHUNKMAX 6400 // >= ceil(1600000/256)=6250
#define STHALF 3200   // half-chunk LDS stage (>= ceil(6250/2)=3125); 25.6KB
#define CEDGE 25      // CHUNKMAX/256: max edges per thread per chunk
#define SEGC 7        // ceil(NBINMAX/256)
#define RSMAX 2048    // per-bin capacity in bins2 (fixed stride) + row_sort LDS stage

typedef short bf16x8 __attribute__((ext_vector_type(8)));
typedef float f32x4 __attribute__((ext_vector_type(4)));

// ---------- bf16 helpers ----------
__device__ __forceinline__ float bf2f(unsigned int lo16) {
  return __uint_as_float((lo16 & 0xffffu) << 16);
}
__device__ __forceinline__ unsigned int f2bf(float x) {  // round-to-nearest-even
  unsigned int u = __float_as_uint(x);
  return (u + 0x7fffu + ((u >> 16) & 1u)) >> 16;
}

// Wave-level inclusive scan (64 lanes).
__device__ __forceinline__ int wave_incl_scan(int v, int lane64) {
  int s = v;
#pragma unroll
  for (int o = 1; o < 64; o <<= 1) {
    int x = __shfl_up(s, o);
    if (lane64 >= o) s += x;
  }
  return s;
}

// ============================ merged sort stage 1 + ALL prep (one launch) ============================
// Blocks [0, 2*NBLKC): chunk->bin sort for both adjacencies (LDS staging is
// LOAD-BEARING -- round-3 lesson: removing it caused 6x write amplification).
// Blocks [2*NBLKC, 2*NBLKC+21): BN fold + W0/W1 bf16 + W2 hi/lo split.
// Blocks [2*NBLKC+21, ...): x*M -> bf16 xm.
// Rationale (r11): prep is independent of the sorts but was serialized before
// them; bin_sort has only 512 blocks (2/CU, LDS-capped) and is atomic/latency
// bound -- prep's BW-bound blocks fill the idle CUs for free.
__global__ __launch_bounds__(256) void sort_prep(
    const int* __restrict__ srcZ, const int* __restrict__ dstZ, const float* __restrict__ valZ,
    const int* __restrict__ srcA, const int* __restrict__ dstA, const float* __restrict__ valA,
    int2* __restrict__ DrmZ, int2* __restrict__ DrmA,
    int2* __restrict__ binsCZ, int2* __restrict__ binsCA,
    int E, int nbin, int chunk,
    const float* b0, const float* g0, const float* be0,
    const float* rm0, const float* rv0,
    const float* b1, const float* g1, const float* be1,
    const float* rm1, const float* rv1,
    float* sc0, float* sh0, float* sc1, float* sh1,
    const float* __restrict__ W0, const float* __restrict__ W1,
    const float* __restrict__ W2,
    unsigned short* __restrict__ Wb0, unsigned short* __restrict__ Wb1,
    unsigned short* __restrict__ W2hi, unsigned short* __restrict__ W2lo,
    const float* __restrict__ x, const float* __restrict__ Mv,
    unsigned short* __restrict__ xm, int n) {
  __shared__ int2 stage[STHALF];
  __shared__ int cur[NBINMAX];
  __shared__ int wsum[4];
  const int t = threadIdx.x;

  if (blockIdx.x >= 2 * NBLKC) {
    int pb = blockIdx.x - 2 * NBLKC;
    if (pb == 0) {  // BN fold
      if (t < 128) {
        float s = g0[t] * rsqrtf(rv0[t] + 1e-5f);
        sc0[t] = s;
        sh0[t] = (b0[t] - rm0[t]) * s + be0[t];
      } else {
        int i = t - 128;
        float s = g1[i] * rsqrtf(rv1[i] + 1e-5f);
        sc1[i] = s;
        sh1[i] = (b1[i] - rm1[i]) * s + be1[i];
      }
      return;
    }
    if (pb <= 20) {  // W conversions
      int i = (pb - 1) * 256 + t;  // 5120 threads, 8 elems each
      if (i < 4096) {
        const float* W = (i < 2048) ? W0 : W1;
        unsigned short* Wb = (i < 2048) ? Wb0 : Wb1;
        int j = (i < 2048) ? i : i - 2048;
        const float4* p = (const float4*)(W + (size_t)j * 8);
        float4 v0 = p[0], v1 = p[1];
        unsigned int o0 = f2bf(v0.x) | (f2bf(v0.y) << 16);
        unsigned int o1 = f2bf(v0.z) | (f2bf(v0.w) << 16);
        unsigned int o2 = f2bf(v1.x) | (f2bf(v1.y) << 16);
        unsigned int o3 = f2bf(v1.z) | (f2bf(v1.w) << 16);
        ((uint4*)Wb)[j] = make_uint4(o0, o1, o2, o3);
      } else {
        int j = i - 4096;  // chunk of 8 within padded 64x128
        int r = j >> 4;    // padded out-row
        float v[8] = {0.f, 0.f, 0.f, 0.f, 0.f, 0.f, 0.f, 0.f};
        if (r < NCLS) {  // j*8 == r*128 + (j&15)*8 exactly
          const float4* p = (const float4*)(W2 + (size_t)j * 8);
          float4 a = p[0], b = p[1];
          v[0] = a.x; v[1] = a.y; v[2] = a.z; v[3] = a.w;
          v[4] = b.x; v[5] = b.y; v[6] = b.z; v[7] = b.w;
        }
        unsigned int h[8], l[8];
#pragma unroll
        for (int q = 0; q < 8; ++q) {
          h[q] = f2bf(v[q]);
          l[q] = f2bf(v[q] - bf2f(h[q]));
        }
        ((uint4*)W2hi)[j] = make_uint4(h[0] | (h[1] << 16), h[2] | (h[3] << 16),
                                       h[4] | (h[5] << 16), h[6] | (h[7] << 16));
        ((uint4*)W2lo)[j] = make_uint4(l[0] | (l[1] << 16), l[2] | (l[3] << 16),
                                       l[4] | (l[5] << 16), l[6] | (l[7] << 16));
      }
      return;
    }
    int i = (pb - 21) * 256 + t;  // one 8-elem chunk per thread
    if (i >= n * (NFEAT / 8)) return;
    int row = i >> 4;
    float m = Mv[row];
    const float4* p = (const float4*)(x + (size_t)i * 8);
    float4 v0 = p[0], v1 = p[1];
    unsigned int o0 = f2bf(v0.x * m) | (f2bf(v0.y * m) << 16);
    unsigned int o1 = f2bf(v0.z * m) | (f2bf(v0.w * m) << 16);
    unsigned int o2 = f2bf(v1.x * m) | (f2bf(v1.y * m) << 16);
    unsigned int o3 = f2bf(v1.z * m) | (f2bf(v1.w * m) << 16);
    ((uint4*)xm)[i] = make_uint4(o0, o1, o2, o3);
    return;
  }

  // ---- bin sort path ----
  int k = blockIdx.x;
  const int* srcp; const int* dstp; const float* valp; int2* Drm; int2* binsC;
  if (k < NBLKC) {
    srcp = srcZ; dstp = dstZ; valp = valZ; Drm = DrmZ; binsC = binsCZ;
  } else {
    k -= NBLKC;
    srcp = srcA; dstp = dstA; valp = valA; Drm = DrmA; binsC = binsCA;
  }
  for (int i = t; i < nbin; i += 256) cur[i] = 0;
  __syncthreads();
  const int e0 = k * chunk, e1 = min(E, e0 + chunk);
  // pass 1: count + capture rank. pk = (bin<<19) | ((d&63)<<13) | rank
  int pk[CEDGE];
#pragma unroll
  for (int j = 0; j < CEDGE; ++j) {
    int e = e0 + t + j * 256;
    if (e < e1) {
      int d = dstp[e];
      int bin = d >> 6;
      int r = atomicAdd(&cur[bin], 1);
      pk[j] = (bin << 19) | ((d & 63) << 13) | r;
    }
  }
  __syncthreads();
  int loc[SEGC], cnt[SEGC];
  int s = 0;
#pragma unroll
  for (int j = 0; j < SEGC; ++j) {
    int i = t * SEGC + j;
    int v = (i < nbin) ? cur[i] : 0;
    loc[j] = s; cnt[j] = v;
    s += v;
  }
  // wave-shfl scan across 256 threads (1 barrier)
  int incl = wave_incl_scan(s, t & 63);
  if ((t & 63) == 63) wsum[t >> 6] = incl;
  __syncthreads();  // wsum ready; all cur reads above done
  int base = 0;
#pragma unroll
  for (int wv = 0; wv < 4; ++wv)
    if (wv < (t >> 6)) base += wsum[wv];
  int ex = base + incl - s;
#pragma unroll
  for (int j = 0; j < SEGC; ++j) {
    int i = t * SEGC + j;
    if (i < nbin) {
      int o = ex + loc[j];
      Drm[(size_t)k * nbin + i] = make_int2(e0 + o, cnt[j]);
      cur[i] = o;
    }
  }
  __syncthreads();
  const int nE = e1 - e0;
  const int hl = (nE + 1) >> 1;  // <= STHALF
  // placement pass A: target position < hl
#pragma unroll
  for (int j = 0; j < CEDGE; ++j) {
    int e = e0 + t + j * 256;
    if (e < e1) {
      int v = pk[j];
      int p = cur[(unsigned)v >> 19] + (v & 0x1FFF);
      if (p < hl)
        stage[p] = make_int2(srcp[e] | (((v >> 13) & 63) << 17), __float_as_int(valp[e]));
    }
  }
  __syncthreads();
  for (int i = t; i < hl; i += 256) binsC[e0 + i] = stage[i];
  __syncthreads();
  // placement pass B: target position >= hl
#pragma unroll
  for (int j = 0; j < CEDGE; ++j) {
    int e = e0 + t + j * 256;
    if (e < e1) {
      int v = pk[j];
      int p = cur[(unsigned)v >> 19] + (v & 0x1FFF);
      if (p >= hl)
        stage[p - hl] = make_int2(srcp[e] | (((v >> 13) & 63) << 17), __float_as_int(valp[e]));
    }
  }
  __syncthreads();
  for (int i = t; i < nE - hl; i += 256) binsC[e0 + hl + i] = stage[i];
}

// ============================ stage 2 (merged Z+A): bin -> full dst-row sort ============================
// bins2 layout: bin b occupies [b*RSMAX, b*RSMAX+cnt). rowdesc[row] = (start, deg).
// r9: bijective XCD swizzle (consecutive bins share an XCD's L2 for the strided
// Drm lines + adjacent binsC runs). r10: wave-shfl scan (1 barrier).
__global__ __launch_bounds__(256) void row_sort2(
    const int2* __restrict__ DrmZ, const int2* __restrict__ DrmA,
    const int2* __restrict__ binsCZ, const int2* __restrict__ binsCA,
    int2* __restrict__ bins2Z, int2* __restrict__ bins2A,
    int2* __restrict__ rdZ, int2* __restrict__ rdA, int n, int nbin) {
  __shared__ int2 stage[RSMAX];
  __shared__ short rankArr[RSMAX];
  __shared__ int wsum[4];
  __shared__ int rcnt[BINROWS];
  __shared__ int roff[BINROWS];
  // bijective XCD swizzle (nwg = 2*nbin, not multiple of 8 -> m204 formula)
  const int nwg = 2 * nbin;
  const int q = nwg >> 3, r = nwg & 7;
  const int xcd = blockIdx.x & 7, idx = blockIdx.x >> 3;
  int b = (xcd < r ? xcd * (q + 1) : r * (q + 1) + (xcd - r) * q) + idx;
  const int t = threadIdx.x;
  const int2* Drm; const int2* binsC; int2* bins2; int2* rowdesc;
  if (b < nbin) {
    Drm = DrmZ; binsC = binsCZ; bins2 = bins2Z; rowdesc = rdZ;
  } else {
    b -= nbin;
    Drm = DrmA; binsC = binsCA; bins2 = bins2A; rowdesc = rdA;
  }
  if (t < BINROWS) rcnt[t] = 0;
  int2 run = Drm[(size_t)t * nbin + b];  // strided read (chunk-major)
  int incl = wave_incl_scan(run.y, t & 63);
  if ((t & 63) == 63) wsum[t >> 6] = incl;
  __syncthreads();  // wsum ready + rcnt zeroed
  int base = 0;
#pragma unroll
  for (int wv = 0; wv < 4; ++wv)
    if (wv < (t >> 6)) base += wsum[wv];
  int mystart = base + incl - run.y;
  int totalAll = wsum[0] + wsum[1] + wsum[2] + wsum[3];
  for (int j = 0; j < run.y; ++j) {
    int2 en = binsC[run.x + j];
    int idx2 = mystart + j;
    int rr = atomicAdd(&rcnt[(en.x >> 17) & 63], 1);
    if (idx2 < RSMAX) {
      stage[idx2] = en;
      rankArr[idx2] = (short)rr;
    }
  }
  __syncthreads();
  const int bs = b * RSMAX;
  if (t < BINROWS) {  // wave 0 only: scan 64 row counts
    int c = rcnt[t];
    int s = c;
#pragma unroll
    for (int o = 1; o < 64; o <<= 1) {
      int v = __shfl_up(s, o);
      if (t >= o) s += v;
    }
    int excl = s - c;
    int row = b * BINROWS + t;
    if (row < n) rowdesc[row] = make_int2(bs + excl, c);
    roff[t] = excl;
  }
  __syncthreads();
  int total = min(totalAll, RSMAX);
  for (int i = t; i < total; i += 256) {
    int2 en = stage[i];
    int row = (en.x >> 17) & 63;
    bins2[bs + roff[row] + rankArr[i]] = en;  // atomic-free scatter
  }
}

// ============================ SPMM (128 feats), row-sorted, no LDS ============================
// [SACRED inner body: round-0 form. Rewrites r1/r2 and wave-serialization r6
//  all regressed -- 100K independent waves is the design. Do not touch.]
template <bool SCALE>
__global__ __launch_bounds__(128) void spmm128_sorted(
    const int2* __restrict__ rowdesc, const int2* __restrict__ bins2,
    const unsigned short* __restrict__ X, const float* __restrict__ AM,
    unsigned short* __restrict__ Y, int n) {
  int row = (blockIdx.x * 128 + threadIdx.x) >> 6;
  int lane = threadIdx.x & 63;
  if (row >= n) return;
  int2 rd = rowdesc[row];
  int s = rd.x, d = rd.y;
  int half = lane >> 5, l32 = lane & 31;
  float s0 = 0.f, s1 = 0.f, s2 = 0.f, s3 = 0.f;
  for (int kb = 0; kb < d; kb += 64) {
    int rem = min(64, d - kb);
    int2 my = (lane < rem) ? bins2[s + kb + lane] : make_int2(0, 0);  // w==0 pads
    int myc = my.x & 0x1FFFF;
    float myw = __int_as_float(my.y);
    for (int k = 0; k < rem; k += 8) {
#pragma unroll
      for (int st = 0; st < 4; ++st) {
        int idx = k + 2 * st + half;  // <= 63; pad entries have w==0
        int c = __shfl(myc, idx);
        float wv = __shfl(myw, idx);
        uint2 pv = *(const uint2*)(X + (size_t)c * NFEAT + l32 * 4);
        s0 += wv * bf2f(pv.x);
        s1 += wv * bf2f(pv.x >> 16);
        s2 += wv * bf2f(pv.y);
        s3 += wv * bf2f(pv.y >> 16);
      }
    }
  }
  s0 += __shfl_xor(s0, 32); s1 += __shfl_xor(s1, 32);
  s2 += __shfl_xor(s2, 32); s3 += __shfl_xor(s3, 32);
  if (SCALE) {
    float am = AM[row];
    s0 *= am; s1 *= am; s2 *= am; s3 *= am;
  }
  unsigned int pk = half ? (f2bf(s2) | (f2bf(s3) << 16)) : (f2bf(s0) | (f2bf(s1) << 16));
  ((unsigned int*)Y)[(size_t)row * (NFEAT / 2) + l32 * 2 + half] = pk;
}

// ============================ MFMA GEMM 128x128 (+BN+ReLU), flat IO ============================
// FUSE_G2=false (layer 0): Out = relu(bn(Y@W^T)) as bf16.
// FUSE_G2=true  (layer 1): H1 = relu(bn(Y@W1^T)) stays on-chip (LDS transpose
// staging), then G2[M x 40] (80B rows) = H1 @ W2^T (hi+lo bf16 split).
template <bool FUSE_G2>
__global__ __launch_bounds__(256) void gemm_mfma128(
    const unsigned short* __restrict__ Y, const unsigned short* __restrict__ Wb,
    const float* __restrict__ scale, const float* __restrict__ shift,
    unsigned short* __restrict__ Out,
    const unsigned short* __restrict__ Whi, const unsigned short* __restrict__ Wlo,
    unsigned short* __restrict__ G2, int M) {
  const int wave = threadIdx.x >> 6;
  const int lane = threadIdx.x & 63;
  const int quad = lane >> 4;
  const int l16 = lane & 15;
  const int arow = blockIdx.x * 64 + wave * 16 + l16;
  const bool rv = arow < M;

  f32x4 acc[8];
#pragma unroll
  for (int c = 0; c < 8; ++c) acc[c] = (f32x4){0.f, 0.f, 0.f, 0.f};

#pragma unroll
  for (int kc = 0; kc < 128; kc += 32) {
    bf16x8 a = rv ? *(const bf16x8*)(Y + (size_t)arow * 128 + kc + quad * 8)
                  : (bf16x8){0, 0, 0, 0, 0, 0, 0, 0};
#pragma unroll
    for (int c = 0; c < 8; ++c) {
      bf16x8 b = *(const bf16x8*)(Wb + (size_t)(c * 16 + l16) * 128 + kc + quad * 8);
      acc[c] = __builtin_amdgcn_mfma_f32_16x16x32_bf16(a, b, acc[c], 0, 0, 0);
    }
  }

  const int orow0 = blockIdx.x * 64 + wave * 16 + quad * 4;

  if constexpr (!FUSE_G2) {
#pragma unroll
    for (int c = 0; c < 8; ++c) {
      int col = c * 16 + l16;
      float sc = scale[col], sh = shift[col];
#pragma unroll
      for (int r = 0; r < 4; ++r) {
        int orow = orow0 + r;
        if (orow < M) {
          float v = fmaxf(acc[c][r] * sc + sh, 0.f);
          Out[(size_t)orow * 128 + col] = (unsigned short)f2bf(v);
        }
      }
    }
  } else {
    __shared__ unsigned short Ht[64][136];
    const int lrow0 = wave * 16 + quad * 4;
#pragma unroll
    for (int c = 0; c < 8; ++c) {
      int col = c * 16 + l16;
      float sc = scale[col], sh = shift[col];
#pragma unroll
      for (int r = 0; r < 4; ++r) {
        float v = fmaxf(acc[c][r] * sc + sh, 0.f);
        Ht[lrow0 + r][col] = (unsigned short)f2bf(v);
      }
    }
    __syncthreads();
    bf16x8 af[4];
#pragma unroll
    for (int kc = 0; kc < 4; ++kc)
      af[kc] = *(const bf16x8*)(&Ht[wave * 16 + l16][kc * 32 + quad * 8]);
    f32x4 acc2[3];
#pragma unroll
    for (int c2 = 0; c2 < 3; ++c2) acc2[c2] = (f32x4){0.f, 0.f, 0.f, 0.f};
#pragma unroll
    for (int kc = 0; kc < 4; ++kc) {
#pragma unroll
      for (int c2 = 0; c2 < 3; ++c2) {
        bf16x8 bh = *(const bf16x8*)(Whi + (size_t)(c2 * 16 + l16) * 128 + kc * 32 + quad * 8);
        bf16x8 bl = *(const bf16x8*)(Wlo + (size_t)(c2 * 16 + l16) * 128 + kc * 32 + quad * 8);
        acc2[c2] = __builtin_amdgcn_mfma_f32_16x16x32_bf16(af[kc], bh, acc2[c2], 0, 0, 0);
        acc2[c2] = __builtin_amdgcn_mfma_f32_16x16x32_bf16(af[kc], bl, acc2[c2], 0, 0, 0);
      }
    }
#pragma unroll
    for (int c2 = 0; c2 < 3; ++c2) {
      int col = c2 * 16 + l16;
      if (col < NCLS) {
#pragma unroll
        for (int r = 0; r < 4; ++r) {
          int orow = orow0 + r;
          if (orow < M) G2[(size_t)orow * NCLS + col] = (unsigned short)f2bf(acc2[c2][r]);
        }
      }
    }
  }
}

// ============================ final: spmm(40) + bias + log_softmax ============================
// G2 rows are 40 bf16 (80B). Gather by lanes q<10 only (10 x 8B = one row).
__global__ __launch_bounds__(128) void spmm_softmax64(
    const int2* __restrict__ rowdesc, const int2* __restrict__ bins2,
    const unsigned short* __restrict__ G2, const float* __restrict__ b2,
    float* __restrict__ out, int n) {
  int row = (blockIdx.x * 128 + threadIdx.x) >> 6;
  int lane = threadIdx.x & 63;
  if (row >= n) return;
  const int eidx = lane >> 4, q = lane & 15;
  const bool vq = q < (NCLS / 4);  // 10 quartets cover the 40 real classes
  float4 bv = vq ? *(const float4*)(b2 + q * 4) : make_float4(0.f, 0.f, 0.f, 0.f);

  int2 rdv = rowdesc[row];
  int s0i = rdv.x, d = rdv.y;
  float a0 = 0.f, a1 = 0.f, a2 = 0.f, a3 = 0.f;
  for (int kb = 0; kb < d; kb += 64) {
    int rem = min(64, d - kb);
    int2 my = (lane < rem) ? bins2[s0i + kb + lane] : make_int2(0, 0);
    int myc = my.x & 0x1FFFF;
    float myw = __int_as_float(my.y);
    int steps = (rem + 3) >> 2;
#pragma unroll 4
    for (int st = 0; st < steps; ++st) {
      int idx = st * 4 + eidx;  // <= 63; pad entries have w==0
      int c = __shfl(myc, idx);
      float wv = __shfl(myw, idx);
      if (vq) {
        uint2 pv = *(const uint2*)(G2 + (size_t)c * NCLS + q * 4);
        a0 += wv * bf2f(pv.x);
        a1 += wv * bf2f(pv.x >> 16);
        a2 += wv * bf2f(pv.y);
        a3 += wv * bf2f(pv.y >> 16);
      }
    }
  }
  a0 += __shfl_xor(a0, 16); a1 += __shfl_xor(a1, 16);
  a2 += __shfl_xor(a2, 16); a3 += __shfl_xor(a3, 16);
  a0 += __shfl_xor(a0, 32); a1 += __shfl_xor(a1, 32);
  a2 += __shfl_xor(a2, 32); a3 += __shfl_xor(a3, 32);
  float z0 = a0 + bv.x, z1 = a1 + bv.y, z2 = a2 + bv.z, z3 = a3 + bv.w;
  bool par = (eidx == 0) && vq;
  float m = par ? fmaxf(fmaxf(z0, z1), fmaxf(z2, z3)) : -INFINITY;
#pragma unroll
  for (int o = 1; o < 64; o <<= 1) m = fmaxf(m, __shfl_xor(m, o));
  float ex = par ? (__expf(z0 - m) + __expf(z1 - m) + __expf(z2 - m) + __expf(z3 - m)) : 0.f;
#pragma unroll
  for (int o = 1; o < 64; o <<= 1) ex += __shfl_xor(ex, o);
  float lg = m + __logf(ex);
  if (par) {
    *(float4*)&out[(size_t)row * NCLS + q * 4] =
        make_float4(z0 - lg, z1 - lg, z2 - lg, z3 - lg);
  }
}

// ============================ launch ============================

extern "C" void kernel_launch(void* const* d_in, const int* in_sizes, int n_in,
                              void* d_out, int out_size, void* d_ws, size_t ws_size,
                              hipStream_t stream) {
  const float* x    = (const float*)d_in[0];
  const float* Mv   = (const float*)d_in[1];
  const float* AM   = (const float*)d_in[2];
  const int* srcZ   = (const int*)d_in[3];
  const int* dstZ   = (const int*)d_in[4];
  const float* valsZ= (const float*)d_in[5];
  const int* src    = (const int*)d_in[6];
  const int* dst    = (const int*)d_in[7];
  const float* vals = (const float*)d_in[8];
  const float* W0   = (const float*)d_in[9];
  const float* b0   = (const float*)d_in[10];
  const float* g0   = (const float*)d_in[11];
  const float* be0  = (const float*)d_in[12];
  const float* rm0  = (const float*)d_in[13];
  const float* rv0  = (const float*)d_in[14];
  const float* W1   = (const float*)d_in[15];
  const float* b1   = (const float*)d_in[16];
  const float* g1   = (const float*)d_in[17];
  const float* be1  = (const float*)d_in[18];
  const float* rm1  = (const float*)d_in[19];
  const float* rv1  = (const float*)d_in[20];
  const float* W2   = (const float*)d_in[21];
  const float* b2   = (const float*)d_in[22];
  float* out = (float*)d_out;

  const int N = in_sizes[1];  // M has shape (N,1)
  const int E = in_sizes[3];
  const int NBIN = (N + BINROWS - 1) / BINROWS;
  const int CHUNK = (E + NBLKC - 1) / NBLKC;  // 6250 <= CHUNKMAX

  char* w = (char*)d_ws;
  size_t off = 0;
  auto alloc = [&](size_t bytes) -> void* {
    void* p = w + off;
    off = (off + bytes + 255) & ~(size_t)255;
    return p;
  };
  const size_t bins2Bytes = (size_t)NBIN * RSMAX * 8;     // 25.6MB fixed-stride layout
  const size_t bufBytes = (size_t)N * NFEAT * 2;          // 25.6MB
  int2* binsCZ = (int2*)alloc((size_t)NBLKC * CHUNK * 8); // 12.8MB chunk-ordered stage (Z)
  int2* binsCA = (int2*)alloc((size_t)NBLKC * CHUNK * 8); // 12.8MB chunk-ordered stage (A)
  int2* bins2A = (int2*)alloc(bins2Bytes);                // lives to the end
  int2* rdZ = (int2*)alloc((size_t)N * 8);                // rowdesc (start,deg) Z
  int2* rdA = (int2*)alloc((size_t)N * 8);                // rowdesc (start,deg) A
  unsigned short* xm = (unsigned short*)alloc(bufBytes);  // 25.6MB
  unsigned short* bufA = (unsigned short*)alloc(bufBytes);                 // Drm -> Y0 -> Y1
  unsigned short* bufB = (unsigned short*)alloc(bins2Bytes > bufBytes ? bins2Bytes : bufBytes);
  float* sc0 = (float*)alloc(128 * 4);
  float* sh0 = (float*)alloc(128 * 4);
  float* sc1 = (float*)alloc(128 * 4);
  float* sh1 = (float*)alloc(128 * 4);
  unsigned short* Wb0 = (unsigned short*)alloc(128 * 128 * 2);
  unsigned short* Wb1 = (unsigned short*)alloc(128 * 128 * 2);
  unsigned short* W2hi = (unsigned short*)alloc(64 * 128 * 2);
  unsigned short* W2lo = (unsigned short*)alloc(64 * 128 * 2);
  // aliases:
  //  - DrmZ/DrmA (3.2MB each) live in bufA until row_sort2 done; spmmZ then
  //    writes Y0 into bufA.
  //  - bins2Z (25.6MB fixed-stride) lives in bufB until spmmZ consumes it
  //    (gemm0 then overwrites bufB with H0); G2 (N x 40 bf16 = 8MB) lives in
  //    bufB after H0 dies (fused gemm1 reads Y1 from bufA, writes G2 to bufB).
  const size_t drmBytes = (size_t)NBLKC * NBIN * 8;  // 3,201,024 (mult of 256)
  int2* DrmZ = (int2*)((char*)bufA + 0 * drmBytes);
  int2* DrmA = (int2*)((char*)bufA + 1 * drmBytes);
  int2* bins2Z = (int2*)bufB;
  unsigned short* G2 = bufB;

  const int RB2 = (N + 1) / 2;  // 2 rows (waves) per 128-thread block
  const int GB64 = (N + 63) / 64;
  const int CONVB = (N * (NFEAT / 8) + 255) / 256;

  // merged: bin-sort (blocks 0..511) + all prep (blocks 512..) in ONE launch --
  // prep fills the CUs the LDS-capped, latency-bound sort leaves idle.
  sort_prep<<<2 * NBLKC + 21 + CONVB, 256, 0, stream>>>(
      srcZ, dstZ, valsZ, src, dst, vals, DrmZ, DrmA, binsCZ, binsCA, E, NBIN, CHUNK,
      b0, g0, be0, rm0, rv0, b1, g1, be1, rm1, rv1, sc0, sh0, sc1, sh1,
      W0, W1, W2, Wb0, Wb1, W2hi, W2lo, x, Mv, xm, N);

  row_sort2<<<2 * NBIN, 256, 0, stream>>>(DrmZ, DrmA, binsCZ, binsCA,
                                          bins2Z, bins2A, rdZ, rdA, N, NBIN);

  // layer 0: Y0 = spmm(adjZ, M*x)*AM ; H0 = relu(bn(Y0 @ W0^T + b0))
  spmm128_sorted<true><<<RB2, 128, 0, stream>>>(rdZ, bins2Z, xm, AM, bufA, N);
  gemm_mfma128<false><<<GB64, 256, 0, stream>>>(bufA, Wb0, sc0, sh0, bufB,
                                                nullptr, nullptr, nullptr, N);

  // layer 1+2: Y1 = spmm(adj, H0) ; fused: H1 = relu(bn(Y1 @ W1^T + b1)) on-chip,
  // G2 = bf16(H1 @ W2^T) (40 cols, 80B rows) written directly.
  spmm128_sorted<false><<<RB2, 128, 0, stream>>>(rdA, bins2A, bufB,
                                                 (const float*)nullptr, bufA, N);
  gemm_mfma128<true><<<GB64, 256, 0, stream>>>(bufA, Wb1, sc1, sh1, nullptr,
                                               W2hi, W2lo, G2, N);

  // out = log_softmax(spmm(adj, G2) + b2)
  spmm_softmax64<<<RB2, 128, 0, stream>>>(rdA, bins2A, G2, b2, out, N);
}